// Round 12
// baseline (89.892 us; speedup 1.0000x reference)
//
#include <hip/hip_runtime.h>
#include <hip/hip_bf16.h>
#include <hip/hip_fp16.h>

#define A_NUM 128
#define U_NUM 8
#define ANT 64
#define D2 64
#define H_DIM 256
#define NUE 1024
#define E_INT 131072

typedef __attribute__((ext_vector_type(8))) short bf16x8_t;
typedef __attribute__((ext_vector_type(4))) short bf16x4_t;
typedef __attribute__((ext_vector_type(4))) float f32x4_t;

// round-to-nearest-even f32 -> bf16
static __device__ inline unsigned short f2bf(float x) {
    unsigned int u = __float_as_uint(x);
    unsigned int r = (u + 0x7fffu + ((u >> 16) & 1u)) >> 16;
    return (unsigned short)r;
}
static __device__ inline unsigned int pack2(float a, float b) {
    return (unsigned int)f2bf(a) | ((unsigned int)f2bf(b) << 16);
}
static __device__ inline unsigned int packh2(float a, float b) {
    return (unsigned int)__half_as_ushort(__float2half(a)) |
           ((unsigned int)__half_as_ushort(__float2half(b)) << 16);
}
// relu + cvt to l2 B-frag (k = lk*4 + i matches rows r of l1T output)
static __device__ inline bf16x4_t relu_cvt4(f32x4_t v) {
    float t0 = v[0] > 0.f ? v[0] : 0.f;
    float t1 = v[1] > 0.f ? v[1] : 0.f;
    float t2 = v[2] > 0.f ? v[2] : 0.f;
    float t3 = v[3] > 0.f ? v[3] : 0.f;
    union { unsigned int u[2]; bf16x4_t s; } r;
    r.u[0] = pack2(t0, t1);
    r.u[1] = pack2(t2, t3);
    return r.s;
}

// ---------------------------------------------------------------------------
// Kernel A: prep. blocks 0..127: Sa[a,h]. blocks 128..255: fragment-order
// bf16 weight packs WpF (l1 A-frags) / W2F (l2 A-frags, K=16 layout).
// (W1 weights are consumed in natural layout by dlink_norm -> no transposes.)
// ---------------------------------------------------------------------------
__global__ void prep_kernel(const float* __restrict__ pv_re, const float* __restrict__ pv_im,
                            const float* __restrict__ W2a, const float* __restrict__ b2a,
                            const float* __restrict__ W2b,
                            float* __restrict__ Sa, unsigned short* __restrict__ WpF,
                            unsigned short* __restrict__ W2F) {
    int bid = blockIdx.x, t = threadIdx.x;
    if (bid < A_NUM) {
        __shared__ float sre[ANT], sim[ANT];
        if (t < ANT) {
            float s = 0.f;
            for (int u = 0; u < U_NUM; ++u) s += pv_re[bid * 512 + u * 64 + t];
            sre[t] = s;
        } else if (t < 2 * ANT) {
            int ant = t - ANT;
            float s = 0.f;
            for (int u = 0; u < U_NUM; ++u) s += pv_im[bid * 512 + u * 64 + ant];
            sim[ant] = s;
        }
        __syncthreads();
        float a0 = 0.f, a1 = 0.f, a2 = 0.f, a3 = 0.f;
        for (int ant = 0; ant < ANT; ant += 2) {
            a0 += sre[ant] * W2a[(64 + ant) * H_DIM + t];
            a1 += sim[ant] * W2a[(192 + ant) * H_DIM + t];
            a2 += sre[ant + 1] * W2a[(64 + ant + 1) * H_DIM + t];
            a3 += sim[ant + 1] * W2a[(192 + ant + 1) * H_DIM + t];
        }
        Sa[bid * H_DIM + t] = b2a[t] + ((a0 + a2) + (a1 + a3));
    } else {
        // 128 blocks cover 49152 pack elements (<=2 per thread)
        for (int f = (bid - A_NUM) * 256 + t; f < 32768 + 16384; f += 128 * 256) {
            if (f < 32768) {  // WpF (l1 A-frags, K=32 layout)
                int i = f & 7, lml = (f >> 3) & 15, lkl = (f >> 7) & 3;
                int kc = (f >> 9) & 3, ht8 = (f >> 11) & 7, hh = (f >> 14) & 1;
                int h = hh * 128 + ht8 * 16 + lml;
                int k = kc * 32 + lkl * 8 + i;
                int row = (k < 64) ? k : (k + 64);
                WpF[f] = f2bf(W2a[row * H_DIM + h]);
            } else {          // W2F (l2 A-frags, K=16 layout)
                int f2 = f - 32768;
                int i = f2 & 3, ll = (f2 >> 2) & 63;
                int dt = (f2 >> 8) & 3, ht8 = (f2 >> 10) & 7, hh = (f2 >> 13) & 1;
                int d = dt * 16 + (ll & 15);
                int k = hh * 128 + ht8 * 16 + (ll >> 4) * 4 + i;
                W2F[f2] = f2bf(W2b[k * D2 + d]);
            }
        }
    }
}

// ---------------------------------------------------------------------------
// Kernel B: big edge MLP (R9 structure — measured best: 4 waves/SIMD).
// Grid 512 = 16 jt(64j) x 2 hh x 16 ac, 512 thr (8 waves = 2 jw x 4 hw),
// exactly 2 blocks/CU. l1 swapped (D1T = Wp x F^T) feeds l2 16x16x16 B-frags
// in registers; hw k-split partials folded via the dead F buffer. LDS 65KB.
// ---------------------------------------------------------------------------
__global__ __launch_bounds__(512) void mlp2_kernel(
        const float* __restrict__ plre, const float* __restrict__ plim,
        const float* __restrict__ Sa, const unsigned short* __restrict__ WpF,
        const unsigned short* __restrict__ W2F, float* __restrict__ partial,
        unsigned short* __restrict__ Pws) {
    __shared__ __attribute__((aligned(16))) unsigned short Wl[16384];   // 32KB
    __shared__ __attribute__((aligned(16))) unsigned short W2l[8192];   // 16KB
    __shared__ __attribute__((aligned(16))) unsigned short Fbuf[8704];  // [64 j][136 k] 17KB
    int bid = blockIdx.x;
    int ac = bid >> 5, hh = (bid >> 4) & 1, jtile = bid & 15;
    int j0 = jtile * 64, a0 = ac * 8;
    int t = threadIdx.x, l = t & 63, lm = l & 15, lk = l >> 4;
    int wv = t >> 6, jw = wv >> 2, hw = wv & 3;

    // ---- stage this hh-half's weights into LDS (once) ----
    {
        const uint4* sW = reinterpret_cast<const uint4*>(WpF + hh * 16384);
        const uint4* sW2 = reinterpret_cast<const uint4*>(W2F + hh * 8192);
        uint4* dW = reinterpret_cast<uint4*>(Wl);
        uint4* dW2 = reinterpret_cast<uint4*>(W2l);
        for (int q = t; q < 3072; q += 512) {
            if (q < 2048) dW[q] = sW[q];
            else dW2[q - 2048] = sW2[q - 2048];
        }
    }

    // ---- staging identity: thread t -> (row er, 16-col segment sg) ----
    int er = t >> 3, sg = t & 7;
    const float* sb = (sg < 4) ? plre : plim;
    int soff = (j0 + er) * 64 + (sg & 3) * 16;
    int fw = er * 136 + ((sg < 4) ? 0 : 64) + (sg & 3) * 16;

    f32x4_t acc2[4][2];  // [dt][jt], accumulated over (a, ht)
#pragma unroll
    for (int dt = 0; dt < 4; ++dt)
#pragma unroll
        for (int jt = 0; jt < 2; ++jt) acc2[dt][jt] = (f32x4_t){0.f, 0.f, 0.f, 0.f};

    float4 s0, s1, s2, s3;
    {   // stage a0 directly
        const float* p = sb + (size_t)a0 * 65536 + soff;
        s0 = *reinterpret_cast<const float4*>(p);
        s1 = *reinterpret_cast<const float4*>(p + 4);
        s2 = *reinterpret_cast<const float4*>(p + 8);
        s3 = *reinterpret_cast<const float4*>(p + 12);
        *reinterpret_cast<uint4*>(&Fbuf[fw]) =
            make_uint4(pack2(s0.x, s0.y), pack2(s0.z, s0.w),
                       pack2(s1.x, s1.y), pack2(s1.z, s1.w));
        *reinterpret_cast<uint4*>(&Fbuf[fw + 8]) =
            make_uint4(pack2(s2.x, s2.y), pack2(s2.z, s2.w),
                       pack2(s3.x, s3.y), pack2(s3.z, s3.w));
    }
    {   // prefetch a1
        const float* p = sb + (size_t)(a0 + 1) * 65536 + soff;
        s0 = *reinterpret_cast<const float4*>(p);
        s1 = *reinterpret_cast<const float4*>(p + 4);
        s2 = *reinterpret_cast<const float4*>(p + 8);
        s3 = *reinterpret_cast<const float4*>(p + 12);
    }
    __syncthreads();  // weights + F(a0) visible

    for (int ai = 0; ai < 8; ++ai) {
        int a = a0 + ai;
        // ---- P emit (hh==0): P[e][ant] = re^2 + im^2 (fp16) ----
        if (hh == 0) {
            uint4 rr = *reinterpret_cast<const uint4*>(Fbuf + er * 136 + sg * 8);
            uint4 ri = *reinterpret_cast<const uint4*>(Fbuf + er * 136 + 64 + sg * 8);
            const unsigned short* pr = (const unsigned short*)&rr;
            const unsigned short* pi = (const unsigned short*)&ri;
            unsigned int pk[4];
#pragma unroll
            for (int i = 0; i < 4; ++i) {
                float re0 = __uint_as_float(((unsigned int)pr[2 * i]) << 16);
                float im0 = __uint_as_float(((unsigned int)pi[2 * i]) << 16);
                float re1 = __uint_as_float(((unsigned int)pr[2 * i + 1]) << 16);
                float im1 = __uint_as_float(((unsigned int)pi[2 * i + 1]) << 16);
                pk[i] = packh2(re0 * re0 + im0 * im0, re1 * re1 + im1 * im1);
            }
            *reinterpret_cast<uint4*>(&Pws[(unsigned)(a * 1024 + j0 + er) * 64 + sg * 8]) =
                make_uint4(pk[0], pk[1], pk[2], pk[3]);
        }
        // ---- layer 1 (swapped): D1T[h][j], wave tile 32h x 32j ----
        f32x4_t acc1[2][2];  // [ht][jt]
#pragma unroll
        for (int ht = 0; ht < 2; ++ht) {
            f32x4_t sa = *reinterpret_cast<const f32x4_t*>(
                Sa + a * H_DIM + hh * 128 + hw * 32 + ht * 16 + lk * 4);
            acc1[ht][0] = sa;
            acc1[ht][1] = sa;
        }
#pragma unroll
        for (int kc = 0; kc < 4; ++kc) {
            bf16x8_t aw0 = *reinterpret_cast<const bf16x8_t*>(
                Wl + (((hw * 2 + 0) * 4 + kc) << 9) + l * 8);
            bf16x8_t aw1 = *reinterpret_cast<const bf16x8_t*>(
                Wl + (((hw * 2 + 1) * 4 + kc) << 9) + l * 8);
            bf16x8_t bf0 = *reinterpret_cast<const bf16x8_t*>(
                Fbuf + (jw * 32 + lm) * 136 + kc * 32 + lk * 8);
            bf16x8_t bf1 = *reinterpret_cast<const bf16x8_t*>(
                Fbuf + (jw * 32 + 16 + lm) * 136 + kc * 32 + lk * 8);
            acc1[0][0] = __builtin_amdgcn_mfma_f32_16x16x32_bf16(aw0, bf0, acc1[0][0], 0, 0, 0);
            acc1[0][1] = __builtin_amdgcn_mfma_f32_16x16x32_bf16(aw0, bf1, acc1[0][1], 0, 0, 0);
            acc1[1][0] = __builtin_amdgcn_mfma_f32_16x16x32_bf16(aw1, bf0, acc1[1][0], 0, 0, 0);
            acc1[1][1] = __builtin_amdgcn_mfma_f32_16x16x32_bf16(aw1, bf1, acc1[1][1], 0, 0, 0);
        }
        // ---- layer 2: relu+cvt in-register, 16x16x16 MFMA, K=16 per ht ----
#pragma unroll
        for (int ht = 0; ht < 2; ++ht) {
            bf16x4_t hl0 = relu_cvt4(acc1[ht][0]);
            bf16x4_t hl1 = relu_cvt4(acc1[ht][1]);
#pragma unroll
            for (int dt = 0; dt < 4; ++dt) {
                bf16x4_t w2 = *reinterpret_cast<const bf16x4_t*>(
                    W2l + (((hw * 2 + ht) * 4 + dt) << 8) + l * 4);
                acc2[dt][0] = __builtin_amdgcn_mfma_f32_16x16x16bf16_1k(w2, hl0, acc2[dt][0], 0, 0, 0);
                acc2[dt][1] = __builtin_amdgcn_mfma_f32_16x16x16bf16_1k(w2, hl1, acc2[dt][1], 0, 0, 0);
            }
        }
        // ---- restage F for a+1 (single buffer, 2 barriers) ----
        if (ai < 7) {
            __syncthreads();  // all F reads done
            *reinterpret_cast<uint4*>(&Fbuf[fw]) =
                make_uint4(pack2(s0.x, s0.y), pack2(s0.z, s0.w),
                           pack2(s1.x, s1.y), pack2(s1.z, s1.w));
            *reinterpret_cast<uint4*>(&Fbuf[fw + 8]) =
                make_uint4(pack2(s2.x, s2.y), pack2(s2.z, s2.w),
                           pack2(s3.x, s3.y), pack2(s3.z, s3.w));
            if (ai < 6) {
                const float* p = sb + (size_t)(a0 + ai + 2) * 65536 + soff;
                s0 = *reinterpret_cast<const float4*>(p);
                s1 = *reinterpret_cast<const float4*>(p + 4);
                s2 = *reinterpret_cast<const float4*>(p + 8);
                s3 = *reinterpret_cast<const float4*>(p + 12);
            }
            __syncthreads();  // F(a+1) ready
        }
    }

    // ---- fold hw-partials via dead F buffer ([64 j][68 d] f32 = 17408B) ----
    float* R = reinterpret_cast<float*>(Fbuf);
#define STORE_R()                                                              \
    do {                                                                       \
        _Pragma("unroll") for (int dt = 0; dt < 4; ++dt)                       \
            _Pragma("unroll") for (int jt = 0; jt < 2; ++jt)                   \
                *reinterpret_cast<f32x4_t*>(                                   \
                    &R[(jw * 32 + jt * 16 + lm) * 68 + dt * 16 + lk * 4]) =    \
                    acc2[dt][jt];                                              \
    } while (0)
#define ADD_R()                                                                \
    do {                                                                       \
        _Pragma("unroll") for (int dt = 0; dt < 4; ++dt)                       \
            _Pragma("unroll") for (int jt = 0; jt < 2; ++jt)                   \
                acc2[dt][jt] += *reinterpret_cast<const f32x4_t*>(             \
                    &R[(jw * 32 + jt * 16 + lm) * 68 + dt * 16 + lk * 4]);     \
    } while (0)
    __syncthreads();
    if (hw == 1) STORE_R();
    __syncthreads();
    if (hw == 0) ADD_R();
    __syncthreads();
    if (hw == 3) STORE_R();
    __syncthreads();
    if (hw == 2) ADD_R();
    __syncthreads();
    if (hw == 2) STORE_R();
    __syncthreads();
    if (hw == 0) {
        ADD_R();
#pragma unroll
        for (int dt = 0; dt < 4; ++dt)
#pragma unroll
            for (int jt = 0; jt < 2; ++jt)
                *reinterpret_cast<float4*>(
                    &partial[(size_t)(hh * 16 + ac) * 65536 +
                             (j0 + jw * 32 + jt * 16 + lm) * 64 + dt * 16 + lk * 4]) =
                    *reinterpret_cast<float4*>(&acc2[dt][jt]);
    }
#undef STORE_R
#undef ADD_R
}

// ---------------------------------------------------------------------------
// Kernel C: fused d-link MLP + per-AP normalization. One block per AP,
// 512 threads. W1a/W1b read in NATURAL layout -> wave-coalesced weight
// loads, feat/h1 as LDS broadcasts. Folds the 32-chunk partial reduction.
// ---------------------------------------------------------------------------
__global__ __launch_bounds__(512) void dlink_norm(
        const float* __restrict__ pv_re, const float* __restrict__ pv_im,
        const float* __restrict__ pldre, const float* __restrict__ pldim,
        const float* __restrict__ partial, const float* __restrict__ b2b,
        const float* __restrict__ W1a, const float* __restrict__ b1a,
        const float* __restrict__ W1b, const float* __restrict__ b1b,
        float* __restrict__ Q, float* __restrict__ out) {
    int a = blockIdx.x, t = threadIdx.x, w = t >> 6, l = t & 63;
    __shared__ float pvr[512], pvi[512], pldr[512], pldi[512];
    __shared__ float nrm[8][8];
    __shared__ __attribute__((aligned(16))) float feat[8][200];
    __shared__ __attribute__((aligned(16))) float h1[8][260];
    __shared__ __attribute__((aligned(16))) float o1[8][128];
    __shared__ float redn[8];
    __shared__ float SshInv;

    pvr[t] = pv_re[a * 512 + t];
    pvi[t] = pv_im[a * 512 + t];
    pldr[t] = pldre[a * 512 + t];
    pldi[t] = pldim[a * 512 + t];
    {   // mlp_ue_all for this AP's 8 rows
        float acc = 128.f * b2b[t & 63];
#pragma unroll
        for (int c = 0; c < 32; ++c) acc += partial[c * 65536 + a * 512 + t];
        feat[t >> 6][129 + (t & 63)] = acc;
    }
    __syncthreads();
    feat[t >> 6][1 + (t & 63)] = pldr[t];
    feat[t >> 6][65 + (t & 63)] = pldi[t];
#pragma unroll
    for (int p = 0; p < 8; ++p) {
        int idx = w * 8 + p;
        int el = idx >> 3, u = idx & 7;
        float pr = pvr[u * 64 + l], pi = pvi[u * 64 + l];
        float qr = pldr[el * 64 + l], qi = pldi[el * 64 + l];
        float ir = pr * qr + pi * qi;   // conj(pv)*pl
        float ii = pr * qi - pi * qr;
        for (int m = 1; m < 64; m <<= 1) {
            ir += __shfl_xor(ir, m, 64);
            ii += __shfl_xor(ii, m, 64);
        }
        if (l == 0) nrm[el][u] = ir * ir + ii * ii;
    }
    __syncthreads();
    if (t < 8) {   // in_infer: exclude u == e % U == el
        float s = 0.f;
        for (int u = 0; u < 8; ++u)
            if (u != t) s += nrm[t][u];
        feat[t][0] = s;
    }
    __syncthreads();
    // ---- layer 1: h = t&255 (coalesced W1a), 4 edges per thread ----
    {
        int h = t & 255, eg = t >> 8;  // eg 0..1 -> edges eg*4 .. eg*4+3
        const float* f0 = feat[eg * 4 + 0];
        const float* f1 = feat[eg * 4 + 1];
        const float* f2 = feat[eg * 4 + 2];
        const float* f3 = feat[eg * 4 + 3];
        float a0 = 0.f, a1 = 0.f, a2 = 0.f, a3 = 0.f;
#pragma unroll 4
        for (int k = 0; k < 193; ++k) {
            float wv = W1a[k * 256 + h];
            a0 = fmaf(wv, f0[k], a0);
            a1 = fmaf(wv, f1[k], a1);
            a2 = fmaf(wv, f2[k], a2);
            a3 = fmaf(wv, f3[k], a3);
        }
        float bb = b1a[h];
        float s0 = bb + a0, s1 = bb + a1, s2 = bb + a2, s3 = bb + a3;
        h1[eg * 4 + 0][h] = s0 > 0.f ? s0 : 0.f;
        h1[eg * 4 + 1][h] = s1 > 0.f ? s1 : 0.f;
        h1[eg * 4 + 2][h] = s2 > 0.f ? s2 : 0.f;
        h1[eg * 4 + 3][h] = s3 > 0.f ? s3 : 0.f;
    }
    __syncthreads();
    // ---- layer 2: c = t&127 (coalesced W1b), 2 edges per thread ----
    {
        int c = t & 127, eg = t >> 7;  // eg 0..3 -> edges eg*2, eg*2+1
        const float* g0 = h1[eg * 2 + 0];
        const float* g1 = h1[eg * 2 + 1];
        float a0 = 0.f, a1 = 0.f;
#pragma unroll 4
        for (int k = 0; k < 256; ++k) {
            float wv = W1b[k * 128 + c];
            a0 = fmaf(wv, g0[k], a0);
            a1 = fmaf(wv, g1[k], a1);
        }
        float bb = b1b[c];
        o1[eg * 2 + 0][c] = bb + a0;
        o1[eg * 2 + 1][c] = bb + a1;
    }
    __syncthreads();
    // ---- normalization ----
    {
        int el = t >> 6, ant = t & 63;
        float re = o1[el][ant], im = o1[el][64 + ant];
        float v = sqrtf(re * re + im * im);
        for (int m = 1; m < 64; m <<= 1) v += __shfl_xor(v, m, 64);
        if (l == 0) redn[w] = v;
    }
    __syncthreads();
    if (t == 0) {
        float S = redn[0] + redn[1] + redn[2] + redn[3] +
                  redn[4] + redn[5] + redn[6] + redn[7];
        SshInv = 1.f / S;
    }
    __syncthreads();
    {
        float inv = SshInv;
        int el = t >> 6, ant = t & 63;
        out[a * 512 + t] = o1[el][ant] * inv;
        out[65536 + a * 512 + t] = o1[el][64 + ant] * inv;
        if (t < 64) {   // Q = |sum_u pv_new|^2
            float sr = 0.f, si = 0.f;
#pragma unroll
            for (int u = 0; u < 8; ++u) {
                sr += o1[u][t];
                si += o1[u][64 + t];
            }
            sr *= inv;
            si *= inv;
            Q[a * 64 + t] = sr * sr + si * si;
        }
    }
}

// ---------------------------------------------------------------------------
// Kernel D: final aggregate from fp16 P (16.8 MB). One wave per j.
// ---------------------------------------------------------------------------
__global__ __launch_bounds__(256) void final_agg(const unsigned short* __restrict__ Pws,
                                                 const float* __restrict__ Qv,
                                                 float* __restrict__ out) {
    int bid = blockIdx.x, t = threadIdx.x, w = t >> 6, l = t & 63;
    __shared__ __attribute__((aligned(16))) float Qc[128][68];
    for (int i = t; i < 8192; i += 256) Qc[i >> 6][i & 63] = Qv[i];
    __syncthreads();
    int j = bid * 4 + w;
    int as = l >> 3, og = l & 7;
    float acc = 0.f;
#pragma unroll 4
    for (int ab = 0; ab < 16; ++ab) {
        int aa = ab * 8 + as;
        uint4 pv4 = *reinterpret_cast<const uint4*>(&Pws[(unsigned)(aa * 1024 + j) * 64 + og * 8]);
        float4 q0 = *reinterpret_cast<const float4*>(&Qc[aa][og * 8]);
        float4 q1 = *reinterpret_cast<const float4*>(&Qc[aa][og * 8 + 4]);
        const unsigned short* hp = (const unsigned short*)&pv4;
        acc += __half2float(__ushort_as_half(hp[0])) * q0.x;
        acc += __half2float(__ushort_as_half(hp[1])) * q0.y;
        acc += __half2float(__ushort_as_half(hp[2])) * q0.z;
        acc += __half2float(__ushort_as_half(hp[3])) * q0.w;
        acc += __half2float(__ushort_as_half(hp[4])) * q1.x;
        acc += __half2float(__ushort_as_half(hp[5])) * q1.y;
        acc += __half2float(__ushort_as_half(hp[6])) * q1.z;
        acc += __half2float(__ushort_as_half(hp[7])) * q1.w;
    }
    for (int m = 1; m < 64; m <<= 1) acc += __shfl_xor(acc, m, 64);
    if (l == 0) out[131072 + j] = acc;
}

extern "C" void kernel_launch(void* const* d_in, const int* in_sizes, int n_in,
                              void* d_out, int out_size, void* d_ws, size_t ws_size,
                              hipStream_t stream) {
    const float* plre = (const float*)d_in[0];
    const float* plim = (const float*)d_in[1];
    const float* pldre = (const float*)d_in[2];
    const float* pldim = (const float*)d_in[3];
    const float* pvre = (const float*)d_in[4];
    const float* pvim = (const float*)d_in[5];
    const float* W2a = (const float*)d_in[6];
    const float* b2a = (const float*)d_in[7];
    const float* W2b = (const float*)d_in[8];
    const float* b2b = (const float*)d_in[9];
    const float* W1a = (const float*)d_in[10];
    const float* b1a = (const float*)d_in[11];
    const float* W1b = (const float*)d_in[12];
    const float* b1b = (const float*)d_in[13];

    char* ws = (char*)d_ws;
    float* Sa = (float*)(ws);                               // 131072 B
    unsigned short* WpF = (unsigned short*)(ws + 131072);   // 65536 B
    unsigned short* W2F = (unsigned short*)(ws + 196608);   // 32768 B
    float* Q = (float*)(ws + 229376);                       // 32768 B
    float* partial = (float*)(ws + 262144);                 // 8388608 B (32 chunks)
    unsigned short* Pws = (unsigned short*)(ws + 8650752);  // 16777216 B
    float* out = (float*)d_out;

    prep_kernel<<<256, 256, 0, stream>>>(pvre, pvim, W2a, b2a, W2b, Sa, WpF, W2F);
    mlp2_kernel<<<512, 512, 0, stream>>>(plre, plim, Sa, WpF, W2F, partial, Pws);
    dlink_norm<<<128, 512, 0, stream>>>(pvre, pvim, pldre, pldim, partial, b2b,
                                        W1a, b1a, W1b, b1b, Q, out);
    final_agg<<<256, 256, 0, stream>>>(Pws, Q, out);
}

// Round 13
// 83.339 us; speedup vs baseline: 1.0786x; 1.0786x over previous
//
#include <hip/hip_runtime.h>
#include <hip/hip_bf16.h>
#include <hip/hip_fp16.h>

#define A_NUM 128
#define U_NUM 8
#define ANT 64
#define D2 64
#define H_DIM 256
#define NUE 1024
#define E_INT 131072

typedef __attribute__((ext_vector_type(8))) short bf16x8_t;
typedef __attribute__((ext_vector_type(4))) short bf16x4_t;
typedef __attribute__((ext_vector_type(4))) float f32x4_t;

// round-to-nearest-even f32 -> bf16
static __device__ inline unsigned short f2bf(float x) {
    unsigned int u = __float_as_uint(x);
    unsigned int r = (u + 0x7fffu + ((u >> 16) & 1u)) >> 16;
    return (unsigned short)r;
}
static __device__ inline unsigned int pack2(float a, float b) {
    return (unsigned int)f2bf(a) | ((unsigned int)f2bf(b) << 16);
}
static __device__ inline unsigned int packh2(float a, float b) {
    return (unsigned int)__half_as_ushort(__float2half(a)) |
           ((unsigned int)__half_as_ushort(__float2half(b)) << 16);
}
// relu + cvt to l2 B-frag (k = lk*4 + i matches rows r of l1T output)
static __device__ inline bf16x4_t relu_cvt4(f32x4_t v) {
    float t0 = v[0] > 0.f ? v[0] : 0.f;
    float t1 = v[1] > 0.f ? v[1] : 0.f;
    float t2 = v[2] > 0.f ? v[2] : 0.f;
    float t3 = v[3] > 0.f ? v[3] : 0.f;
    union { unsigned int u[2]; bf16x4_t s; } r;
    r.u[0] = pack2(t0, t1);
    r.u[1] = pack2(t2, t3);
    return r.s;
}

// ---------------------------------------------------------------------------
// Kernel A: prep. blocks 0..127: Sa[a,h]. blocks 128..255: fragment-order
// bf16 weight packs WpF (l1 A-frags) / W2F (l2 A-frags, K=16 layout).
// ---------------------------------------------------------------------------
__global__ void prep_kernel(const float* __restrict__ pv_re, const float* __restrict__ pv_im,
                            const float* __restrict__ W2a, const float* __restrict__ b2a,
                            const float* __restrict__ W2b,
                            float* __restrict__ Sa, unsigned short* __restrict__ WpF,
                            unsigned short* __restrict__ W2F) {
    int bid = blockIdx.x, t = threadIdx.x;
    if (bid < A_NUM) {
        __shared__ float sre[ANT], sim[ANT];
        if (t < ANT) {
            float s = 0.f;
            for (int u = 0; u < U_NUM; ++u) s += pv_re[bid * 512 + u * 64 + t];
            sre[t] = s;
        } else if (t < 2 * ANT) {
            int ant = t - ANT;
            float s = 0.f;
            for (int u = 0; u < U_NUM; ++u) s += pv_im[bid * 512 + u * 64 + ant];
            sim[ant] = s;
        }
        __syncthreads();
        float a0 = 0.f, a1 = 0.f, a2 = 0.f, a3 = 0.f;
        for (int ant = 0; ant < ANT; ant += 2) {
            a0 += sre[ant] * W2a[(64 + ant) * H_DIM + t];
            a1 += sim[ant] * W2a[(192 + ant) * H_DIM + t];
            a2 += sre[ant + 1] * W2a[(64 + ant + 1) * H_DIM + t];
            a3 += sim[ant + 1] * W2a[(192 + ant + 1) * H_DIM + t];
        }
        Sa[bid * H_DIM + t] = b2a[t] + ((a0 + a2) + (a1 + a3));
    } else {
        for (int f = (bid - A_NUM) * 256 + t; f < 32768 + 16384; f += 128 * 256) {
            if (f < 32768) {  // WpF (l1 A-frags, K=32 layout)
                int i = f & 7, lml = (f >> 3) & 15, lkl = (f >> 7) & 3;
                int kc = (f >> 9) & 3, ht8 = (f >> 11) & 7, hh = (f >> 14) & 1;
                int h = hh * 128 + ht8 * 16 + lml;
                int k = kc * 32 + lkl * 8 + i;
                int row = (k < 64) ? k : (k + 64);
                WpF[f] = f2bf(W2a[row * H_DIM + h]);
            } else {          // W2F (l2 A-frags, K=16 layout)
                int f2 = f - 32768;
                int i = f2 & 3, ll = (f2 >> 2) & 63;
                int dt = (f2 >> 8) & 3, ht8 = (f2 >> 10) & 7, hh = (f2 >> 13) & 1;
                int d = dt * 16 + (ll & 15);
                int k = hh * 128 + ht8 * 16 + (ll >> 4) * 4 + i;
                W2F[f2] = f2bf(W2b[k * D2 + d]);
            }
        }
    }
}

// ---------------------------------------------------------------------------
// Kernel B: big edge MLP (R9 structure — measured best: 4 waves/SIMD).
// Grid 512 = 16 jt(64j) x 2 hh x 16 ac, 512 thr (8 waves = 2 jw x 4 hw).
// ---------------------------------------------------------------------------
__global__ __launch_bounds__(512) void mlp2_kernel(
        const float* __restrict__ plre, const float* __restrict__ plim,
        const float* __restrict__ Sa, const unsigned short* __restrict__ WpF,
        const unsigned short* __restrict__ W2F, float* __restrict__ partial,
        unsigned short* __restrict__ Pws) {
    __shared__ __attribute__((aligned(16))) unsigned short Wl[16384];   // 32KB
    __shared__ __attribute__((aligned(16))) unsigned short W2l[8192];   // 16KB
    __shared__ __attribute__((aligned(16))) unsigned short Fbuf[8704];  // [64 j][136 k] 17KB
    int bid = blockIdx.x;
    int ac = bid >> 5, hh = (bid >> 4) & 1, jtile = bid & 15;
    int j0 = jtile * 64, a0 = ac * 8;
    int t = threadIdx.x, l = t & 63, lm = l & 15, lk = l >> 4;
    int wv = t >> 6, jw = wv >> 2, hw = wv & 3;

    {
        const uint4* sW = reinterpret_cast<const uint4*>(WpF + hh * 16384);
        const uint4* sW2 = reinterpret_cast<const uint4*>(W2F + hh * 8192);
        uint4* dW = reinterpret_cast<uint4*>(Wl);
        uint4* dW2 = reinterpret_cast<uint4*>(W2l);
        for (int q = t; q < 3072; q += 512) {
            if (q < 2048) dW[q] = sW[q];
            else dW2[q - 2048] = sW2[q - 2048];
        }
    }

    int er = t >> 3, sg = t & 7;
    const float* sb = (sg < 4) ? plre : plim;
    int soff = (j0 + er) * 64 + (sg & 3) * 16;
    int fw = er * 136 + ((sg < 4) ? 0 : 64) + (sg & 3) * 16;

    f32x4_t acc2[4][2];
#pragma unroll
    for (int dt = 0; dt < 4; ++dt)
#pragma unroll
        for (int jt = 0; jt < 2; ++jt) acc2[dt][jt] = (f32x4_t){0.f, 0.f, 0.f, 0.f};

    float4 s0, s1, s2, s3;
    {
        const float* p = sb + (size_t)a0 * 65536 + soff;
        s0 = *reinterpret_cast<const float4*>(p);
        s1 = *reinterpret_cast<const float4*>(p + 4);
        s2 = *reinterpret_cast<const float4*>(p + 8);
        s3 = *reinterpret_cast<const float4*>(p + 12);
        *reinterpret_cast<uint4*>(&Fbuf[fw]) =
            make_uint4(pack2(s0.x, s0.y), pack2(s0.z, s0.w),
                       pack2(s1.x, s1.y), pack2(s1.z, s1.w));
        *reinterpret_cast<uint4*>(&Fbuf[fw + 8]) =
            make_uint4(pack2(s2.x, s2.y), pack2(s2.z, s2.w),
                       pack2(s3.x, s3.y), pack2(s3.z, s3.w));
    }
    {
        const float* p = sb + (size_t)(a0 + 1) * 65536 + soff;
        s0 = *reinterpret_cast<const float4*>(p);
        s1 = *reinterpret_cast<const float4*>(p + 4);
        s2 = *reinterpret_cast<const float4*>(p + 8);
        s3 = *reinterpret_cast<const float4*>(p + 12);
    }
    __syncthreads();

    for (int ai = 0; ai < 8; ++ai) {
        int a = a0 + ai;
        if (hh == 0) {
            uint4 rr = *reinterpret_cast<const uint4*>(Fbuf + er * 136 + sg * 8);
            uint4 ri = *reinterpret_cast<const uint4*>(Fbuf + er * 136 + 64 + sg * 8);
            const unsigned short* pr = (const unsigned short*)&rr;
            const unsigned short* pi = (const unsigned short*)&ri;
            unsigned int pk[4];
#pragma unroll
            for (int i = 0; i < 4; ++i) {
                float re0 = __uint_as_float(((unsigned int)pr[2 * i]) << 16);
                float im0 = __uint_as_float(((unsigned int)pi[2 * i]) << 16);
                float re1 = __uint_as_float(((unsigned int)pr[2 * i + 1]) << 16);
                float im1 = __uint_as_float(((unsigned int)pi[2 * i + 1]) << 16);
                pk[i] = packh2(re0 * re0 + im0 * im0, re1 * re1 + im1 * im1);
            }
            *reinterpret_cast<uint4*>(&Pws[(unsigned)(a * 1024 + j0 + er) * 64 + sg * 8]) =
                make_uint4(pk[0], pk[1], pk[2], pk[3]);
        }
        f32x4_t acc1[2][2];
#pragma unroll
        for (int ht = 0; ht < 2; ++ht) {
            f32x4_t sa = *reinterpret_cast<const f32x4_t*>(
                Sa + a * H_DIM + hh * 128 + hw * 32 + ht * 16 + lk * 4);
            acc1[ht][0] = sa;
            acc1[ht][1] = sa;
        }
#pragma unroll
        for (int kc = 0; kc < 4; ++kc) {
            bf16x8_t aw0 = *reinterpret_cast<const bf16x8_t*>(
                Wl + (((hw * 2 + 0) * 4 + kc) << 9) + l * 8);
            bf16x8_t aw1 = *reinterpret_cast<const bf16x8_t*>(
                Wl + (((hw * 2 + 1) * 4 + kc) << 9) + l * 8);
            bf16x8_t bf0 = *reinterpret_cast<const bf16x8_t*>(
                Fbuf + (jw * 32 + lm) * 136 + kc * 32 + lk * 8);
            bf16x8_t bf1 = *reinterpret_cast<const bf16x8_t*>(
                Fbuf + (jw * 32 + 16 + lm) * 136 + kc * 32 + lk * 8);
            acc1[0][0] = __builtin_amdgcn_mfma_f32_16x16x32_bf16(aw0, bf0, acc1[0][0], 0, 0, 0);
            acc1[0][1] = __builtin_amdgcn_mfma_f32_16x16x32_bf16(aw0, bf1, acc1[0][1], 0, 0, 0);
            acc1[1][0] = __builtin_amdgcn_mfma_f32_16x16x32_bf16(aw1, bf0, acc1[1][0], 0, 0, 0);
            acc1[1][1] = __builtin_amdgcn_mfma_f32_16x16x32_bf16(aw1, bf1, acc1[1][1], 0, 0, 0);
        }
#pragma unroll
        for (int ht = 0; ht < 2; ++ht) {
            bf16x4_t hl0 = relu_cvt4(acc1[ht][0]);
            bf16x4_t hl1 = relu_cvt4(acc1[ht][1]);
#pragma unroll
            for (int dt = 0; dt < 4; ++dt) {
                bf16x4_t w2 = *reinterpret_cast<const bf16x4_t*>(
                    W2l + (((hw * 2 + ht) * 4 + dt) << 8) + l * 4);
                acc2[dt][0] = __builtin_amdgcn_mfma_f32_16x16x16bf16_1k(w2, hl0, acc2[dt][0], 0, 0, 0);
                acc2[dt][1] = __builtin_amdgcn_mfma_f32_16x16x16bf16_1k(w2, hl1, acc2[dt][1], 0, 0, 0);
            }
        }
        if (ai < 7) {
            __syncthreads();
            *reinterpret_cast<uint4*>(&Fbuf[fw]) =
                make_uint4(pack2(s0.x, s0.y), pack2(s0.z, s0.w),
                           pack2(s1.x, s1.y), pack2(s1.z, s1.w));
            *reinterpret_cast<uint4*>(&Fbuf[fw + 8]) =
                make_uint4(pack2(s2.x, s2.y), pack2(s2.z, s2.w),
                           pack2(s3.x, s3.y), pack2(s3.z, s3.w));
            if (ai < 6) {
                const float* p = sb + (size_t)(a0 + ai + 2) * 65536 + soff;
                s0 = *reinterpret_cast<const float4*>(p);
                s1 = *reinterpret_cast<const float4*>(p + 4);
                s2 = *reinterpret_cast<const float4*>(p + 8);
                s3 = *reinterpret_cast<const float4*>(p + 12);
            }
            __syncthreads();
        }
    }

    float* R = reinterpret_cast<float*>(Fbuf);
#define STORE_R()                                                              \
    do {                                                                       \
        _Pragma("unroll") for (int dt = 0; dt < 4; ++dt)                       \
            _Pragma("unroll") for (int jt = 0; jt < 2; ++jt)                   \
                *reinterpret_cast<f32x4_t*>(                                   \
                    &R[(jw * 32 + jt * 16 + lm) * 68 + dt * 16 + lk * 4]) =    \
                    acc2[dt][jt];                                              \
    } while (0)
#define ADD_R()                                                                \
    do {                                                                       \
        _Pragma("unroll") for (int dt = 0; dt < 4; ++dt)                       \
            _Pragma("unroll") for (int jt = 0; jt < 2; ++jt)                   \
                acc2[dt][jt] += *reinterpret_cast<const f32x4_t*>(             \
                    &R[(jw * 32 + jt * 16 + lm) * 68 + dt * 16 + lk * 4]);     \
    } while (0)
    __syncthreads();
    if (hw == 1) STORE_R();
    __syncthreads();
    if (hw == 0) ADD_R();
    __syncthreads();
    if (hw == 3) STORE_R();
    __syncthreads();
    if (hw == 2) ADD_R();
    __syncthreads();
    if (hw == 2) STORE_R();
    __syncthreads();
    if (hw == 0) {
        ADD_R();
#pragma unroll
        for (int dt = 0; dt < 4; ++dt)
#pragma unroll
            for (int jt = 0; jt < 2; ++jt)
                *reinterpret_cast<float4*>(
                    &partial[(size_t)(hh * 16 + ac) * 65536 +
                             (j0 + jw * 32 + jt * 16 + lm) * 64 + dt * 16 + lk * 4]) =
                    *reinterpret_cast<float4*>(&acc2[dt][jt]);
    }
#undef STORE_R
#undef ADD_R
}

// ---------------------------------------------------------------------------
// Kernel C: fused d-link MLP + per-AP normalization. One block per AP,
// 512 threads. Natural-layout weights, BUT vectorized: lane l owns 4
// consecutive output columns -> float4 per lane AND coalesced per wave;
// feat/h1 are wave-uniform LDS broadcasts. Wave = edge.
// ---------------------------------------------------------------------------
__global__ __launch_bounds__(512) void dlink_norm(
        const float* __restrict__ pv_re, const float* __restrict__ pv_im,
        const float* __restrict__ pldre, const float* __restrict__ pldim,
        const float* __restrict__ partial, const float* __restrict__ b2b,
        const float* __restrict__ W1a, const float* __restrict__ b1a,
        const float* __restrict__ W1b, const float* __restrict__ b1b,
        float* __restrict__ Q, float* __restrict__ out) {
    int a = blockIdx.x, t = threadIdx.x, w = t >> 6, l = t & 63;
    __shared__ float pvr[512], pvi[512], pldr[512], pldi[512];
    __shared__ float nrm[8][8];
    __shared__ __attribute__((aligned(16))) float feat[8][200];
    __shared__ __attribute__((aligned(16))) float h1[8][256];
    __shared__ __attribute__((aligned(16))) float red2[2][8][128];
    __shared__ __attribute__((aligned(16))) float o1[8][128];
    __shared__ float redn[8];
    __shared__ float SshInv;

    pvr[t] = pv_re[a * 512 + t];
    pvi[t] = pv_im[a * 512 + t];
    pldr[t] = pldre[a * 512 + t];
    pldi[t] = pldim[a * 512 + t];
    {   // mlp_ue_all for this AP's 8 rows
        float acc = 128.f * b2b[t & 63];
#pragma unroll
        for (int c = 0; c < 32; ++c) acc += partial[c * 65536 + a * 512 + t];
        feat[t >> 6][129 + (t & 63)] = acc;
    }
    __syncthreads();
    feat[t >> 6][1 + (t & 63)] = pldr[t];
    feat[t >> 6][65 + (t & 63)] = pldi[t];
#pragma unroll
    for (int p = 0; p < 8; ++p) {
        int idx = w * 8 + p;
        int el = idx >> 3, u = idx & 7;
        float pr = pvr[u * 64 + l], pi = pvi[u * 64 + l];
        float qr = pldr[el * 64 + l], qi = pldi[el * 64 + l];
        float ir = pr * qr + pi * qi;   // conj(pv)*pl
        float ii = pr * qi - pi * qr;
        for (int m = 1; m < 64; m <<= 1) {
            ir += __shfl_xor(ir, m, 64);
            ii += __shfl_xor(ii, m, 64);
        }
        if (l == 0) nrm[el][u] = ir * ir + ii * ii;
    }
    __syncthreads();
    if (t < 8) {   // in_infer: exclude u == e % U == el
        float s = 0.f;
        for (int u = 0; u < 8; ++u)
            if (u != t) s += nrm[t][u];
        feat[t][0] = s;
    }
    __syncthreads();
    // ---- layer 1: wave w = edge; lane l -> h = 4l..4l+3 (float4 + coalesced) ----
    {
        const float* fe = feat[w];
        float a0 = 0.f, a1 = 0.f, a2 = 0.f, a3 = 0.f;
#pragma unroll 4
        for (int k = 0; k < 193; ++k) {
            float4 wv = *reinterpret_cast<const float4*>(W1a + k * 256 + l * 4);
            float f = fe[k];
            a0 = fmaf(wv.x, f, a0);
            a1 = fmaf(wv.y, f, a1);
            a2 = fmaf(wv.z, f, a2);
            a3 = fmaf(wv.w, f, a3);
        }
        float4 bb = *reinterpret_cast<const float4*>(b1a + l * 4);
        float s0 = a0 + bb.x, s1 = a1 + bb.y, s2 = a2 + bb.z, s3 = a3 + bb.w;
        *reinterpret_cast<float4*>(&h1[w][l * 4]) =
            make_float4(s0 > 0.f ? s0 : 0.f, s1 > 0.f ? s1 : 0.f,
                        s2 > 0.f ? s2 : 0.f, s3 > 0.f ? s3 : 0.f);
    }
    __syncthreads();
    // ---- layer 2: wave w = edge; lane: kh = l>>5, c = (l&31)*4..+3 ----
    {
        int kh = l >> 5, cq = l & 31;
        const float* g = h1[w] + kh * 128;
        const float* wb = W1b + kh * 128 * 128;
        float a0 = 0.f, a1 = 0.f, a2 = 0.f, a3 = 0.f;
#pragma unroll 4
        for (int k = 0; k < 128; ++k) {
            float4 wv = *reinterpret_cast<const float4*>(wb + k * 128 + cq * 4);
            float f = g[k];
            a0 = fmaf(wv.x, f, a0);
            a1 = fmaf(wv.y, f, a1);
            a2 = fmaf(wv.z, f, a2);
            a3 = fmaf(wv.w, f, a3);
        }
        *reinterpret_cast<float4*>(&red2[kh][w][cq * 4]) = make_float4(a0, a1, a2, a3);
    }
    __syncthreads();
    {   // combine k-halves + bias: 1024 outputs, 2 per thread
        int i0 = t, i1 = t + 512;
        int e0 = i0 >> 7, c0 = i0 & 127, e1 = i1 >> 7, c1 = i1 & 127;
        o1[e0][c0] = b1b[c0] + red2[0][e0][c0] + red2[1][e0][c0];
        o1[e1][c1] = b1b[c1] + red2[0][e1][c1] + red2[1][e1][c1];
    }
    __syncthreads();
    // ---- normalization ----
    {
        int el = t >> 6, ant = t & 63;
        float re = o1[el][ant], im = o1[el][64 + ant];
        float v = sqrtf(re * re + im * im);
        for (int m = 1; m < 64; m <<= 1) v += __shfl_xor(v, m, 64);
        if (l == 0) redn[w] = v;
    }
    __syncthreads();
    if (t == 0) {
        float S = redn[0] + redn[1] + redn[2] + redn[3] +
                  redn[4] + redn[5] + redn[6] + redn[7];
        SshInv = 1.f / S;
    }
    __syncthreads();
    {
        float inv = SshInv;
        int el = t >> 6, ant = t & 63;
        out[a * 512 + t] = o1[el][ant] * inv;
        out[65536 + a * 512 + t] = o1[el][64 + ant] * inv;
        if (t < 64) {   // Q = |sum_u pv_new|^2
            float sr = 0.f, si = 0.f;
#pragma unroll
            for (int u = 0; u < 8; ++u) {
                sr += o1[u][t];
                si += o1[u][64 + t];
            }
            sr *= inv;
            si *= inv;
            Q[a * 64 + t] = sr * sr + si * si;
        }
    }
}

// ---------------------------------------------------------------------------
// Kernel D: final aggregate from fp16 P (16.8 MB). One wave per j.
// ---------------------------------------------------------------------------
__global__ __launch_bounds__(256) void final_agg(const unsigned short* __restrict__ Pws,
                                                 const float* __restrict__ Qv,
                                                 float* __restrict__ out) {
    int bid = blockIdx.x, t = threadIdx.x, w = t >> 6, l = t & 63;
    __shared__ __attribute__((aligned(16))) float Qc[128][68];
    for (int i = t; i < 8192; i += 256) Qc[i >> 6][i & 63] = Qv[i];
    __syncthreads();
    int j = bid * 4 + w;
    int as = l >> 3, og = l & 7;
    float acc = 0.f;
#pragma unroll 4
    for (int ab = 0; ab < 16; ++ab) {
        int aa = ab * 8 + as;
        uint4 pv4 = *reinterpret_cast<const uint4*>(&Pws[(unsigned)(aa * 1024 + j) * 64 + og * 8]);
        float4 q0 = *reinterpret_cast<const float4*>(&Qc[aa][og * 8]);
        float4 q1 = *reinterpret_cast<const float4*>(&Qc[aa][og * 8 + 4]);
        const unsigned short* hp = (const unsigned short*)&pv4;
        acc += __half2float(__ushort_as_half(hp[0])) * q0.x;
        acc += __half2float(__ushort_as_half(hp[1])) * q0.y;
        acc += __half2float(__ushort_as_half(hp[2])) * q0.z;
        acc += __half2float(__ushort_as_half(hp[3])) * q0.w;
        acc += __half2float(__ushort_as_half(hp[4])) * q1.x;
        acc += __half2float(__ushort_as_half(hp[5])) * q1.y;
        acc += __half2float(__ushort_as_half(hp[6])) * q1.z;
        acc += __half2float(__ushort_as_half(hp[7])) * q1.w;
    }
    for (int m = 1; m < 64; m <<= 1) acc += __shfl_xor(acc, m, 64);
    if (l == 0) out[131072 + j] = acc;
}

extern "C" void kernel_launch(void* const* d_in, const int* in_sizes, int n_in,
                              void* d_out, int out_size, void* d_ws, size_t ws_size,
                              hipStream_t stream) {
    const float* plre = (const float*)d_in[0];
    const float* plim = (const float*)d_in[1];
    const float* pldre = (const float*)d_in[2];
    const float* pldim = (const float*)d_in[3];
    const float* pvre = (const float*)d_in[4];
    const float* pvim = (const float*)d_in[5];
    const float* W2a = (const float*)d_in[6];
    const float* b2a = (const float*)d_in[7];
    const float* W2b = (const float*)d_in[8];
    const float* b2b = (const float*)d_in[9];
    const float* W1a = (const float*)d_in[10];
    const float* b1a = (const float*)d_in[11];
    const float* W1b = (const float*)d_in[12];
    const float* b1b = (const float*)d_in[13];

    char* ws = (char*)d_ws;
    float* Sa = (float*)(ws);                               // 131072 B
    unsigned short* WpF = (unsigned short*)(ws + 131072);   // 65536 B
    unsigned short* W2F = (unsigned short*)(ws + 196608);   // 32768 B
    float* Q = (float*)(ws + 229376);                       // 32768 B
    float* partial = (float*)(ws + 262144);                 // 8388608 B (32 chunks)
    unsigned short* Pws = (unsigned short*)(ws + 8650752);  // 16777216 B
    float* out = (float*)d_out;

    prep_kernel<<<256, 256, 0, stream>>>(pvre, pvim, W2a, b2a, W2b, Sa, WpF, W2F);
    mlp2_kernel<<<512, 512, 0, stream>>>(plre, plim, Sa, WpF, W2F, partial, Pws);
    dlink_norm<<<128, 512, 0, stream>>>(pvre, pvim, pldre, pldim, partial, b2b,
                                        W1a, b1a, W1b, b1b, Q, out);
    final_agg<<<256, 256, 0, stream>>>(Pws, Q, out);
}

// Round 14
// 66.260 us; speedup vs baseline: 1.3567x; 1.2578x over previous
//
#include <hip/hip_runtime.h>
#include <hip/hip_bf16.h>
#include <hip/hip_fp16.h>

#define A_NUM 128
#define U_NUM 8
#define ANT 64
#define D2 64
#define H_DIM 256
#define NUE 1024
#define E_INT 131072

typedef __attribute__((ext_vector_type(8))) short bf16x8_t;
typedef __attribute__((ext_vector_type(4))) short bf16x4_t;
typedef __attribute__((ext_vector_type(4))) float f32x4_t;

// round-to-nearest-even f32 -> bf16
static __device__ inline unsigned short f2bf(float x) {
    unsigned int u = __float_as_uint(x);
    unsigned int r = (u + 0x7fffu + ((u >> 16) & 1u)) >> 16;
    return (unsigned short)r;
}
static __device__ inline unsigned int pack2(float a, float b) {
    return (unsigned int)f2bf(a) | ((unsigned int)f2bf(b) << 16);
}
static __device__ inline unsigned int packh2(float a, float b) {
    return (unsigned int)__half_as_ushort(__float2half(a)) |
           ((unsigned int)__half_as_ushort(__float2half(b)) << 16);
}
// relu + cvt to l2 B-frag (k = lk*4 + i matches rows r of l1T output)
static __device__ inline bf16x4_t relu_cvt4(f32x4_t v) {
    float t0 = v[0] > 0.f ? v[0] : 0.f;
    float t1 = v[1] > 0.f ? v[1] : 0.f;
    float t2 = v[2] > 0.f ? v[2] : 0.f;
    float t3 = v[3] > 0.f ? v[3] : 0.f;
    union { unsigned int u[2]; bf16x4_t s; } r;
    r.u[0] = pack2(t0, t1);
    r.u[1] = pack2(t2, t3);
    return r.s;
}

// ---------------------------------------------------------------------------
// Kernel A: prep. blocks 0..127: Sa[a,h]. blocks 128..255: fragment-order
// bf16 weight packs WpF (l1 A-frags) / W2F (l2 A-frags, K=16 layout).
// ---------------------------------------------------------------------------
__global__ void prep_kernel(const float* __restrict__ pv_re, const float* __restrict__ pv_im,
                            const float* __restrict__ W2a, const float* __restrict__ b2a,
                            const float* __restrict__ W2b,
                            float* __restrict__ Sa, unsigned short* __restrict__ WpF,
                            unsigned short* __restrict__ W2F) {
    int bid = blockIdx.x, t = threadIdx.x;
    if (bid < A_NUM) {
        __shared__ float sre[ANT], sim[ANT];
        if (t < ANT) {
            float s = 0.f;
            for (int u = 0; u < U_NUM; ++u) s += pv_re[bid * 512 + u * 64 + t];
            sre[t] = s;
        } else if (t < 2 * ANT) {
            int ant = t - ANT;
            float s = 0.f;
            for (int u = 0; u < U_NUM; ++u) s += pv_im[bid * 512 + u * 64 + ant];
            sim[ant] = s;
        }
        __syncthreads();
        float a0 = 0.f, a1 = 0.f, a2 = 0.f, a3 = 0.f;
        for (int ant = 0; ant < ANT; ant += 2) {
            a0 += sre[ant] * W2a[(64 + ant) * H_DIM + t];
            a1 += sim[ant] * W2a[(192 + ant) * H_DIM + t];
            a2 += sre[ant + 1] * W2a[(64 + ant + 1) * H_DIM + t];
            a3 += sim[ant + 1] * W2a[(192 + ant + 1) * H_DIM + t];
        }
        Sa[bid * H_DIM + t] = b2a[t] + ((a0 + a2) + (a1 + a3));
    } else {
        for (int f = (bid - A_NUM) * 256 + t; f < 32768 + 16384; f += 128 * 256) {
            if (f < 32768) {  // WpF (l1 A-frags, K=32 layout)
                int i = f & 7, lml = (f >> 3) & 15, lkl = (f >> 7) & 3;
                int kc = (f >> 9) & 3, ht8 = (f >> 11) & 7, hh = (f >> 14) & 1;
                int h = hh * 128 + ht8 * 16 + lml;
                int k = kc * 32 + lkl * 8 + i;
                int row = (k < 64) ? k : (k + 64);
                WpF[f] = f2bf(W2a[row * H_DIM + h]);
            } else {          // W2F (l2 A-frags, K=16 layout)
                int f2 = f - 32768;
                int i = f2 & 3, ll = (f2 >> 2) & 63;
                int dt = (f2 >> 8) & 3, ht8 = (f2 >> 10) & 7, hh = (f2 >> 13) & 1;
                int d = dt * 16 + (ll & 15);
                int k = hh * 128 + ht8 * 16 + (ll >> 4) * 4 + i;
                W2F[f2] = f2bf(W2b[k * D2 + d]);
            }
        }
    }
}

// ---------------------------------------------------------------------------
// Kernel B: big edge MLP (R9 structure — measured best: 4 waves/SIMD).
// Grid 512 = 16 jt(64j) x 2 hh x 16 ac, 512 thr (8 waves = 2 jw x 4 hw).
// ---------------------------------------------------------------------------
__global__ __launch_bounds__(512) void mlp2_kernel(
        const float* __restrict__ plre, const float* __restrict__ plim,
        const float* __restrict__ Sa, const unsigned short* __restrict__ WpF,
        const unsigned short* __restrict__ W2F, float* __restrict__ partial,
        unsigned short* __restrict__ Pws) {
    __shared__ __attribute__((aligned(16))) unsigned short Wl[16384];   // 32KB
    __shared__ __attribute__((aligned(16))) unsigned short W2l[8192];   // 16KB
    __shared__ __attribute__((aligned(16))) unsigned short Fbuf[8704];  // [64 j][136 k] 17KB
    int bid = blockIdx.x;
    int ac = bid >> 5, hh = (bid >> 4) & 1, jtile = bid & 15;
    int j0 = jtile * 64, a0 = ac * 8;
    int t = threadIdx.x, l = t & 63, lm = l & 15, lk = l >> 4;
    int wv = t >> 6, jw = wv >> 2, hw = wv & 3;

    {
        const uint4* sW = reinterpret_cast<const uint4*>(WpF + hh * 16384);
        const uint4* sW2 = reinterpret_cast<const uint4*>(W2F + hh * 8192);
        uint4* dW = reinterpret_cast<uint4*>(Wl);
        uint4* dW2 = reinterpret_cast<uint4*>(W2l);
        for (int q = t; q < 3072; q += 512) {
            if (q < 2048) dW[q] = sW[q];
            else dW2[q - 2048] = sW2[q - 2048];
        }
    }

    int er = t >> 3, sg = t & 7;
    const float* sb = (sg < 4) ? plre : plim;
    int soff = (j0 + er) * 64 + (sg & 3) * 16;
    int fw = er * 136 + ((sg < 4) ? 0 : 64) + (sg & 3) * 16;

    f32x4_t acc2[4][2];
#pragma unroll
    for (int dt = 0; dt < 4; ++dt)
#pragma unroll
        for (int jt = 0; jt < 2; ++jt) acc2[dt][jt] = (f32x4_t){0.f, 0.f, 0.f, 0.f};

    float4 s0, s1, s2, s3;
    {
        const float* p = sb + (size_t)a0 * 65536 + soff;
        s0 = *reinterpret_cast<const float4*>(p);
        s1 = *reinterpret_cast<const float4*>(p + 4);
        s2 = *reinterpret_cast<const float4*>(p + 8);
        s3 = *reinterpret_cast<const float4*>(p + 12);
        *reinterpret_cast<uint4*>(&Fbuf[fw]) =
            make_uint4(pack2(s0.x, s0.y), pack2(s0.z, s0.w),
                       pack2(s1.x, s1.y), pack2(s1.z, s1.w));
        *reinterpret_cast<uint4*>(&Fbuf[fw + 8]) =
            make_uint4(pack2(s2.x, s2.y), pack2(s2.z, s2.w),
                       pack2(s3.x, s3.y), pack2(s3.z, s3.w));
    }
    {
        const float* p = sb + (size_t)(a0 + 1) * 65536 + soff;
        s0 = *reinterpret_cast<const float4*>(p);
        s1 = *reinterpret_cast<const float4*>(p + 4);
        s2 = *reinterpret_cast<const float4*>(p + 8);
        s3 = *reinterpret_cast<const float4*>(p + 12);
    }
    __syncthreads();

    for (int ai = 0; ai < 8; ++ai) {
        int a = a0 + ai;
        if (hh == 0) {
            uint4 rr = *reinterpret_cast<const uint4*>(Fbuf + er * 136 + sg * 8);
            uint4 ri = *reinterpret_cast<const uint4*>(Fbuf + er * 136 + 64 + sg * 8);
            const unsigned short* pr = (const unsigned short*)&rr;
            const unsigned short* pi = (const unsigned short*)&ri;
            unsigned int pk[4];
#pragma unroll
            for (int i = 0; i < 4; ++i) {
                float re0 = __uint_as_float(((unsigned int)pr[2 * i]) << 16);
                float im0 = __uint_as_float(((unsigned int)pi[2 * i]) << 16);
                float re1 = __uint_as_float(((unsigned int)pr[2 * i + 1]) << 16);
                float im1 = __uint_as_float(((unsigned int)pi[2 * i + 1]) << 16);
                pk[i] = packh2(re0 * re0 + im0 * im0, re1 * re1 + im1 * im1);
            }
            *reinterpret_cast<uint4*>(&Pws[(unsigned)(a * 1024 + j0 + er) * 64 + sg * 8]) =
                make_uint4(pk[0], pk[1], pk[2], pk[3]);
        }
        f32x4_t acc1[2][2];
#pragma unroll
        for (int ht = 0; ht < 2; ++ht) {
            f32x4_t sa = *reinterpret_cast<const f32x4_t*>(
                Sa + a * H_DIM + hh * 128 + hw * 32 + ht * 16 + lk * 4);
            acc1[ht][0] = sa;
            acc1[ht][1] = sa;
        }
#pragma unroll
        for (int kc = 0; kc < 4; ++kc) {
            bf16x8_t aw0 = *reinterpret_cast<const bf16x8_t*>(
                Wl + (((hw * 2 + 0) * 4 + kc) << 9) + l * 8);
            bf16x8_t aw1 = *reinterpret_cast<const bf16x8_t*>(
                Wl + (((hw * 2 + 1) * 4 + kc) << 9) + l * 8);
            bf16x8_t bf0 = *reinterpret_cast<const bf16x8_t*>(
                Fbuf + (jw * 32 + lm) * 136 + kc * 32 + lk * 8);
            bf16x8_t bf1 = *reinterpret_cast<const bf16x8_t*>(
                Fbuf + (jw * 32 + 16 + lm) * 136 + kc * 32 + lk * 8);
            acc1[0][0] = __builtin_amdgcn_mfma_f32_16x16x32_bf16(aw0, bf0, acc1[0][0], 0, 0, 0);
            acc1[0][1] = __builtin_amdgcn_mfma_f32_16x16x32_bf16(aw0, bf1, acc1[0][1], 0, 0, 0);
            acc1[1][0] = __builtin_amdgcn_mfma_f32_16x16x32_bf16(aw1, bf0, acc1[1][0], 0, 0, 0);
            acc1[1][1] = __builtin_amdgcn_mfma_f32_16x16x32_bf16(aw1, bf1, acc1[1][1], 0, 0, 0);
        }
#pragma unroll
        for (int ht = 0; ht < 2; ++ht) {
            bf16x4_t hl0 = relu_cvt4(acc1[ht][0]);
            bf16x4_t hl1 = relu_cvt4(acc1[ht][1]);
#pragma unroll
            for (int dt = 0; dt < 4; ++dt) {
                bf16x4_t w2 = *reinterpret_cast<const bf16x4_t*>(
                    W2l + (((hw * 2 + ht) * 4 + dt) << 8) + l * 4);
                acc2[dt][0] = __builtin_amdgcn_mfma_f32_16x16x16bf16_1k(w2, hl0, acc2[dt][0], 0, 0, 0);
                acc2[dt][1] = __builtin_amdgcn_mfma_f32_16x16x16bf16_1k(w2, hl1, acc2[dt][1], 0, 0, 0);
            }
        }
        if (ai < 7) {
            __syncthreads();
            *reinterpret_cast<uint4*>(&Fbuf[fw]) =
                make_uint4(pack2(s0.x, s0.y), pack2(s0.z, s0.w),
                           pack2(s1.x, s1.y), pack2(s1.z, s1.w));
            *reinterpret_cast<uint4*>(&Fbuf[fw + 8]) =
                make_uint4(pack2(s2.x, s2.y), pack2(s2.z, s2.w),
                           pack2(s3.x, s3.y), pack2(s3.z, s3.w));
            if (ai < 6) {
                const float* p = sb + (size_t)(a0 + ai + 2) * 65536 + soff;
                s0 = *reinterpret_cast<const float4*>(p);
                s1 = *reinterpret_cast<const float4*>(p + 4);
                s2 = *reinterpret_cast<const float4*>(p + 8);
                s3 = *reinterpret_cast<const float4*>(p + 12);
            }
            __syncthreads();
        }
    }

    float* R = reinterpret_cast<float*>(Fbuf);
#define STORE_R()                                                              \
    do {                                                                       \
        _Pragma("unroll") for (int dt = 0; dt < 4; ++dt)                       \
            _Pragma("unroll") for (int jt = 0; jt < 2; ++jt)                   \
                *reinterpret_cast<f32x4_t*>(                                   \
                    &R[(jw * 32 + jt * 16 + lm) * 68 + dt * 16 + lk * 4]) =    \
                    acc2[dt][jt];                                              \
    } while (0)
#define ADD_R()                                                                \
    do {                                                                       \
        _Pragma("unroll") for (int dt = 0; dt < 4; ++dt)                       \
            _Pragma("unroll") for (int jt = 0; jt < 2; ++jt)                   \
                acc2[dt][jt] += *reinterpret_cast<const f32x4_t*>(             \
                    &R[(jw * 32 + jt * 16 + lm) * 68 + dt * 16 + lk * 4]);     \
    } while (0)
    __syncthreads();
    if (hw == 1) STORE_R();
    __syncthreads();
    if (hw == 0) ADD_R();
    __syncthreads();
    if (hw == 3) STORE_R();
    __syncthreads();
    if (hw == 2) ADD_R();
    __syncthreads();
    if (hw == 2) STORE_R();
    __syncthreads();
    if (hw == 0) {
        ADD_R();
#pragma unroll
        for (int dt = 0; dt < 4; ++dt)
#pragma unroll
            for (int jt = 0; jt < 2; ++jt)
                *reinterpret_cast<float4*>(
                    &partial[(size_t)(hh * 16 + ac) * 65536 +
                             (j0 + jw * 32 + jt * 16 + lm) * 64 + dt * 16 + lk * 4]) =
                    *reinterpret_cast<float4*>(&acc2[dt][jt]);
    }
#undef STORE_R
#undef ADD_R
}

// ---------------------------------------------------------------------------
// Kernel C: fused d-link MLP + per-AP normalization. One block per AP,
// 512 threads. Weight matrices streamed through a 16KB LDS chunk buffer via
// BULK cooperative staging (1024 independent loads/chunk -> cannot be
// latency-serialized), reg-prefetched one chunk ahead. Wave = (edge-pair,
// half): each float2/b32 weight LDS read serves 2 edges.
// ---------------------------------------------------------------------------
__global__ __launch_bounds__(512) void dlink_norm(
        const float* __restrict__ pv_re, const float* __restrict__ pv_im,
        const float* __restrict__ pldre, const float* __restrict__ pldim,
        const float* __restrict__ partial, const float* __restrict__ b2b,
        const float* __restrict__ W1a, const float* __restrict__ b1a,
        const float* __restrict__ W1b, const float* __restrict__ b1b,
        float* __restrict__ Q, float* __restrict__ out) {
    int a = blockIdx.x, t = threadIdx.x, w = t >> 6, l = t & 63;
    __shared__ float pvr[512], pvi[512], pldr[512], pldi[512];
    __shared__ float nrm[8][8];
    __shared__ __attribute__((aligned(16))) float feat[8][208];   // cols 193..207 = 0
    __shared__ __attribute__((aligned(16))) float h1[8][256];
    __shared__ __attribute__((aligned(16))) float o1[8][128];
    __shared__ __attribute__((aligned(16))) float Wbuf[4096];     // 16KB chunk buffer
    __shared__ float redn[8];
    __shared__ float SshInv;

    pvr[t] = pv_re[a * 512 + t];
    pvi[t] = pv_im[a * 512 + t];
    pldr[t] = pldre[a * 512 + t];
    pldi[t] = pldim[a * 512 + t];
    {   // mlp_ue_all for this AP's 8 rows
        float acc = 128.f * b2b[t & 63];
#pragma unroll
        for (int c = 0; c < 32; ++c) acc += partial[c * 65536 + a * 512 + t];
        feat[t >> 6][129 + (t & 63)] = acc;
    }
    if (t < 120) feat[t / 15][193 + t % 15] = 0.f;  // zero pad cols 193..207
    __syncthreads();
    feat[t >> 6][1 + (t & 63)] = pldr[t];
    feat[t >> 6][65 + (t & 63)] = pldi[t];
#pragma unroll
    for (int p = 0; p < 8; ++p) {
        int idx = w * 8 + p;
        int el = idx >> 3, u = idx & 7;
        float pr = pvr[u * 64 + l], pi = pvi[u * 64 + l];
        float qr = pldr[el * 64 + l], qi = pldi[el * 64 + l];
        float ir = pr * qr + pi * qi;   // conj(pv)*pl
        float ii = pr * qi - pi * qr;
        for (int m = 1; m < 64; m <<= 1) {
            ir += __shfl_xor(ir, m, 64);
            ii += __shfl_xor(ii, m, 64);
        }
        if (l == 0) nrm[el][u] = ir * ir + ii * ii;
    }
    __syncthreads();
    if (t < 8) {   // in_infer: exclude u == e % U == el
        float s = 0.f;
        for (int u = 0; u < 8; ++u)
            if (u != t) s += nrm[t][u];
        feat[t][0] = s;
    }
    __syncthreads();

    // ---- layer 1: 13 chunks of 16 k-rows (rows >=193 zeroed) ----
    // wave: pair p = w&3 -> edges 2p,2p+1; half hv = w>>2 -> h = hv*128 + 2l
    {
        int p = w & 3, hv = w >> 2;
        int e0 = 2 * p, e1 = 2 * p + 1;
        const float* f0base = feat[e0];
        const float* f1base = feat[e1];
        float a00 = 0.f, a01 = 0.f, a10 = 0.f, a11 = 0.f;
        int row0 = t >> 6, col0 = (t & 63) * 4;          // idx = t
        int row1 = (t + 512) >> 6, col1 = col0;          // idx = t+512
        float4 pre0, pre1;
        // stage chunk 0
        {
            int g0 = row0, g1 = row1;
            pre0 = (g0 < 193) ? *reinterpret_cast<const float4*>(W1a + g0 * 256 + col0)
                              : make_float4(0.f, 0.f, 0.f, 0.f);
            pre1 = (g1 < 193) ? *reinterpret_cast<const float4*>(W1a + g1 * 256 + col1)
                              : make_float4(0.f, 0.f, 0.f, 0.f);
            *reinterpret_cast<float4*>(&Wbuf[row0 * 256 + col0]) = pre0;
            *reinterpret_cast<float4*>(&Wbuf[row1 * 256 + col1]) = pre1;
        }
        __syncthreads();
        for (int c = 0; c < 13; ++c) {
            if (c < 12) {  // issue next chunk's loads early (latency under compute)
                int g0 = (c + 1) * 16 + row0, g1 = (c + 1) * 16 + row1;
                pre0 = (g0 < 193) ? *reinterpret_cast<const float4*>(W1a + g0 * 256 + col0)
                                  : make_float4(0.f, 0.f, 0.f, 0.f);
                pre1 = (g1 < 193) ? *reinterpret_cast<const float4*>(W1a + g1 * 256 + col1)
                                  : make_float4(0.f, 0.f, 0.f, 0.f);
            }
            // compute chunk c: 16 kk
#pragma unroll
            for (int q = 0; q < 4; ++q) {
                float4 f0 = *reinterpret_cast<const float4*>(f0base + c * 16 + q * 4);
                float4 f1 = *reinterpret_cast<const float4*>(f1base + c * 16 + q * 4);
#pragma unroll
                for (int i = 0; i < 4; ++i) {
                    int kk = q * 4 + i;
                    float2 wv = *reinterpret_cast<const float2*>(&Wbuf[kk * 256 + hv * 128 + l * 2]);
                    float fi0 = (i == 0) ? f0.x : (i == 1) ? f0.y : (i == 2) ? f0.z : f0.w;
                    float fi1 = (i == 0) ? f1.x : (i == 1) ? f1.y : (i == 2) ? f1.z : f1.w;
                    a00 = fmaf(wv.x, fi0, a00);
                    a01 = fmaf(wv.y, fi0, a01);
                    a10 = fmaf(wv.x, fi1, a10);
                    a11 = fmaf(wv.y, fi1, a11);
                }
            }
            __syncthreads();  // chunk c reads done
            if (c < 12) {
                *reinterpret_cast<float4*>(&Wbuf[row0 * 256 + col0]) = pre0;
                *reinterpret_cast<float4*>(&Wbuf[row1 * 256 + col1]) = pre1;
                __syncthreads();  // chunk c+1 staged
            }
        }
        int h = hv * 128 + l * 2;
        float bb0 = b1a[h], bb1 = b1a[h + 1];
        float s00 = a00 + bb0, s01 = a01 + bb1, s10 = a10 + bb0, s11 = a11 + bb1;
        h1[e0][h] = s00 > 0.f ? s00 : 0.f;
        h1[e0][h + 1] = s01 > 0.f ? s01 : 0.f;
        h1[e1][h] = s10 > 0.f ? s10 : 0.f;
        h1[e1][h + 1] = s11 > 0.f ? s11 : 0.f;
    }
    __syncthreads();

    // ---- layer 2: 8 chunks of 32 k-rows of W1b[256][128] ----
    // wave: pair p -> edges 2p,2p+1; half cv = w>>2 -> c = cv*64 + l
    {
        int p = w & 3, cv = w >> 2;
        int e0 = 2 * p, e1 = 2 * p + 1;
        const float* g0base = h1[e0];
        const float* g1base = h1[e1];
        int c = cv * 64 + l;
        float a0 = 0.f, a1 = 0.f;
        int row0 = t >> 5, col0 = (t & 31) * 4;          // idx = t   (rows 0..15)
        int row1 = (t + 512) >> 5, col1 = col0;          // idx = t+512 (rows 16..31)
        float4 pre0, pre1;
        {
            pre0 = *reinterpret_cast<const float4*>(W1b + row0 * 128 + col0);
            pre1 = *reinterpret_cast<const float4*>(W1b + row1 * 128 + col1);
            *reinterpret_cast<float4*>(&Wbuf[row0 * 128 + col0]) = pre0;
            *reinterpret_cast<float4*>(&Wbuf[row1 * 128 + col1]) = pre1;
        }
        __syncthreads();
        for (int ch = 0; ch < 8; ++ch) {
            if (ch < 7) {
                const float* src = W1b + (ch + 1) * 32 * 128;
                pre0 = *reinterpret_cast<const float4*>(src + row0 * 128 + col0);
                pre1 = *reinterpret_cast<const float4*>(src + row1 * 128 + col1);
            }
#pragma unroll
            for (int q = 0; q < 8; ++q) {
                float4 g0 = *reinterpret_cast<const float4*>(g0base + ch * 32 + q * 4);
                float4 g1 = *reinterpret_cast<const float4*>(g1base + ch * 32 + q * 4);
#pragma unroll
                for (int i = 0; i < 4; ++i) {
                    int kk = q * 4 + i;
                    float wv = Wbuf[kk * 128 + c];
                    float gi0 = (i == 0) ? g0.x : (i == 1) ? g0.y : (i == 2) ? g0.z : g0.w;
                    float gi1 = (i == 0) ? g1.x : (i == 1) ? g1.y : (i == 2) ? g1.z : g1.w;
                    a0 = fmaf(wv, gi0, a0);
                    a1 = fmaf(wv, gi1, a1);
                }
            }
            __syncthreads();
            if (ch < 7) {
                *reinterpret_cast<float4*>(&Wbuf[row0 * 128 + col0]) = pre0;
                *reinterpret_cast<float4*>(&Wbuf[row1 * 128 + col1]) = pre1;
                __syncthreads();
            }
        }
        float bb = b1b[c];
        o1[e0][c] = bb + a0;
        o1[e1][c] = bb + a1;
    }
    __syncthreads();

    // ---- normalization ----
    {
        int el = t >> 6, ant = t & 63;
        float re = o1[el][ant], im = o1[el][64 + ant];
        float v = sqrtf(re * re + im * im);
        for (int m = 1; m < 64; m <<= 1) v += __shfl_xor(v, m, 64);
        if (l == 0) redn[w] = v;
    }
    __syncthreads();
    if (t == 0) {
        float S = redn[0] + redn[1] + redn[2] + redn[3] +
                  redn[4] + redn[5] + redn[6] + redn[7];
        SshInv = 1.f / S;
    }
    __syncthreads();
    {
        float inv = SshInv;
        int el = t >> 6, ant = t & 63;
        out[a * 512 + t] = o1[el][ant] * inv;
        out[65536 + a * 512 + t] = o1[el][64 + ant] * inv;
        if (t < 64) {   // Q = |sum_u pv_new|^2
            float sr = 0.f, si = 0.f;
#pragma unroll
            for (int u = 0; u < 8; ++u) {
                sr += o1[u][t];
                si += o1[u][64 + t];
            }
            sr *= inv;
            si *= inv;
            Q[a * 64 + t] = sr * sr + si * si;
        }
    }
}

// ---------------------------------------------------------------------------
// Kernel D: final aggregate from fp16 P (16.8 MB). One wave per j.
// ---------------------------------------------------------------------------
__global__ __launch_bounds__(256) void final_agg(const unsigned short* __restrict__ Pws,
                                                 const float* __restrict__ Qv,
                                                 float* __restrict__ out) {
    int bid = blockIdx.x, t = threadIdx.x, w = t >> 6, l = t & 63;
    __shared__ __attribute__((aligned(16))) float Qc[128][68];
    for (int i = t; i < 8192; i += 256) Qc[i >> 6][i & 63] = Qv[i];
    __syncthreads();
    int j = bid * 4 + w;
    int as = l >> 3, og = l & 7;
    float acc = 0.f;
#pragma unroll 4
    for (int ab = 0; ab < 16; ++ab) {
        int aa = ab * 8 + as;
        uint4 pv4 = *reinterpret_cast<const uint4*>(&Pws[(unsigned)(aa * 1024 + j) * 64 + og * 8]);
        float4 q0 = *reinterpret_cast<const float4*>(&Qc[aa][og * 8]);
        float4 q1 = *reinterpret_cast<const float4*>(&Qc[aa][og * 8 + 4]);
        const unsigned short* hp = (const unsigned short*)&pv4;
        acc += __half2float(__ushort_as_half(hp[0])) * q0.x;
        acc += __half2float(__ushort_as_half(hp[1])) * q0.y;
        acc += __half2float(__ushort_as_half(hp[2])) * q0.z;
        acc += __half2float(__ushort_as_half(hp[3])) * q0.w;
        acc += __half2float(__ushort_as_half(hp[4])) * q1.x;
        acc += __half2float(__ushort_as_half(hp[5])) * q1.y;
        acc += __half2float(__ushort_as_half(hp[6])) * q1.z;
        acc += __half2float(__ushort_as_half(hp[7])) * q1.w;
    }
    for (int m = 1; m < 64; m <<= 1) acc += __shfl_xor(acc, m, 64);
    if (l == 0) out[131072 + j] = acc;
}

extern "C" void kernel_launch(void* const* d_in, const int* in_sizes, int n_in,
                              void* d_out, int out_size, void* d_ws, size_t ws_size,
                              hipStream_t stream) {
    const float* plre = (const float*)d_in[0];
    const float* plim = (const float*)d_in[1];
    const float* pldre = (const float*)d_in[2];
    const float* pldim = (const float*)d_in[3];
    const float* pvre = (const float*)d_in[4];
    const float* pvim = (const float*)d_in[5];
    const float* W2a = (const float*)d_in[6];
    const float* b2a = (const float*)d_in[7];
    const float* W2b = (const float*)d_in[8];
    const float* b2b = (const float*)d_in[9];
    const float* W1a = (const float*)d_in[10];
    const float* b1a = (const float*)d_in[11];
    const float* W1b = (const float*)d_in[12];
    const float* b1b = (const float*)d_in[13];

    char* ws = (char*)d_ws;
    float* Sa = (float*)(ws);                               // 131072 B
    unsigned short* WpF = (unsigned short*)(ws + 131072);   // 65536 B
    unsigned short* W2F = (unsigned short*)(ws + 196608);   // 32768 B
    float* Q = (float*)(ws + 229376);                       // 32768 B
    float* partial = (float*)(ws + 262144);                 // 8388608 B (32 chunks)
    unsigned short* Pws = (unsigned short*)(ws + 8650752);  // 16777216 B
    float* out = (float*)d_out;

    prep_kernel<<<256, 256, 0, stream>>>(pvre, pvim, W2a, b2a, W2b, Sa, WpF, W2F);
    mlp2_kernel<<<512, 512, 0, stream>>>(plre, plim, Sa, WpF, W2F, partial, Pws);
    dlink_norm<<<128, 512, 0, stream>>>(pvre, pvim, pldre, pldim, partial, b2b,
                                        W1a, b1a, W1b, b1b, Q, out);
    final_agg<<<256, 256, 0, stream>>>(Pws, Q, out);
}

// Round 15
// 65.219 us; speedup vs baseline: 1.3783x; 1.0160x over previous
//
#include <hip/hip_runtime.h>
#include <hip/hip_bf16.h>
#include <hip/hip_fp16.h>

#define A_NUM 128
#define U_NUM 8
#define ANT 64
#define D2 64
#define H_DIM 256
#define NUE 1024
#define E_INT 131072

typedef __attribute__((ext_vector_type(8))) short bf16x8_t;
typedef __attribute__((ext_vector_type(4))) short bf16x4_t;
typedef __attribute__((ext_vector_type(4))) float f32x4_t;

// round-to-nearest-even f32 -> bf16
static __device__ inline unsigned short f2bf(float x) {
    unsigned int u = __float_as_uint(x);
    unsigned int r = (u + 0x7fffu + ((u >> 16) & 1u)) >> 16;
    return (unsigned short)r;
}
static __device__ inline unsigned int pack2(float a, float b) {
    return (unsigned int)f2bf(a) | ((unsigned int)f2bf(b) << 16);
}
static __device__ inline unsigned int packh2(float a, float b) {
    return (unsigned int)__half_as_ushort(__float2half(a)) |
           ((unsigned int)__half_as_ushort(__float2half(b)) << 16);
}
// relu + cvt to l2 B-frag (k = lk*4 + i matches rows r of l1T output)
static __device__ inline bf16x4_t relu_cvt4(f32x4_t v) {
    float t0 = v[0] > 0.f ? v[0] : 0.f;
    float t1 = v[1] > 0.f ? v[1] : 0.f;
    float t2 = v[2] > 0.f ? v[2] : 0.f;
    float t3 = v[3] > 0.f ? v[3] : 0.f;
    union { unsigned int u[2]; bf16x4_t s; } r;
    r.u[0] = pack2(t0, t1);
    r.u[1] = pack2(t2, t3);
    return r.s;
}

// swizzled index into an unpadded [64][128] u16 tile: spreads the 16-way
// row-bank alias (256B rows) into free 2-way. 8-aligned col groups stay
// contiguous under the XOR (key touches bits 3-5 only).
#define FIDX(r, c) (((r) << 7) + ((c) ^ (((r) & 7) << 3)))

// ---------------------------------------------------------------------------
// Kernel A: prep. blocks 0..127: Sa[a,h]. blocks 128..255: fragment-order
// bf16 weight packs WpF (l1 A-frags) / W2F (l2 A-frags, K=16 layout).
// ---------------------------------------------------------------------------
__global__ void prep_kernel(const float* __restrict__ pv_re, const float* __restrict__ pv_im,
                            const float* __restrict__ W2a, const float* __restrict__ b2a,
                            const float* __restrict__ W2b,
                            float* __restrict__ Sa, unsigned short* __restrict__ WpF,
                            unsigned short* __restrict__ W2F) {
    int bid = blockIdx.x, t = threadIdx.x;
    if (bid < A_NUM) {
        __shared__ float sre[ANT], sim[ANT];
        if (t < ANT) {
            float s = 0.f;
            for (int u = 0; u < U_NUM; ++u) s += pv_re[bid * 512 + u * 64 + t];
            sre[t] = s;
        } else if (t < 2 * ANT) {
            int ant = t - ANT;
            float s = 0.f;
            for (int u = 0; u < U_NUM; ++u) s += pv_im[bid * 512 + u * 64 + ant];
            sim[ant] = s;
        }
        __syncthreads();
        float a0 = 0.f, a1 = 0.f, a2 = 0.f, a3 = 0.f;
        for (int ant = 0; ant < ANT; ant += 2) {
            a0 += sre[ant] * W2a[(64 + ant) * H_DIM + t];
            a1 += sim[ant] * W2a[(192 + ant) * H_DIM + t];
            a2 += sre[ant + 1] * W2a[(64 + ant + 1) * H_DIM + t];
            a3 += sim[ant + 1] * W2a[(192 + ant + 1) * H_DIM + t];
        }
        Sa[bid * H_DIM + t] = b2a[t] + ((a0 + a2) + (a1 + a3));
    } else {
        for (int f = (bid - A_NUM) * 256 + t; f < 32768 + 16384; f += 128 * 256) {
            if (f < 32768) {  // WpF (l1 A-frags, K=32 layout)
                int i = f & 7, lml = (f >> 3) & 15, lkl = (f >> 7) & 3;
                int kc = (f >> 9) & 3, ht8 = (f >> 11) & 7, hh = (f >> 14) & 1;
                int h = hh * 128 + ht8 * 16 + lml;
                int k = kc * 32 + lkl * 8 + i;
                int row = (k < 64) ? k : (k + 64);
                WpF[f] = f2bf(W2a[row * H_DIM + h]);
            } else {          // W2F (l2 A-frags, K=16 layout)
                int f2 = f - 32768;
                int i = f2 & 3, ll = (f2 >> 2) & 63;
                int dt = (f2 >> 8) & 3, ht8 = (f2 >> 10) & 7, hh = (f2 >> 13) & 1;
                int d = dt * 16 + (ll & 15);
                int k = hh * 128 + ht8 * 16 + (ll >> 4) * 4 + i;
                W2F[f2] = f2bf(W2b[k * D2 + d]);
            }
        }
    }
}

// ---------------------------------------------------------------------------
// Kernel B: big edge MLP (R9 geometry, double-buffered swizzled F).
// Grid 512 = 16 jt(64j) x 2 hh x 16 ac, 512 thr (8 waves = 2 jw x 4 hw),
// 2 blocks/CU (LDS exactly 80KB). ONE barrier per a-iter (was two):
// compute reads F2[cur] while staging writes F2[cur^1].
// ---------------------------------------------------------------------------
__global__ __launch_bounds__(512) void mlp2_kernel(
        const float* __restrict__ plre, const float* __restrict__ plim,
        const float* __restrict__ Sa, const unsigned short* __restrict__ WpF,
        const unsigned short* __restrict__ W2F, float* __restrict__ partial,
        unsigned short* __restrict__ Pws) {
    __shared__ __attribute__((aligned(16))) unsigned short Wl[16384];    // 32KB
    __shared__ __attribute__((aligned(16))) unsigned short W2l[8192];    // 16KB
    __shared__ __attribute__((aligned(16))) unsigned short F2[2][8192];  // 32KB swz [64][128]
    int bid = blockIdx.x;
    int ac = bid >> 5, hh = (bid >> 4) & 1, jtile = bid & 15;
    int j0 = jtile * 64, a0 = ac * 8;
    int t = threadIdx.x, l = t & 63, lm = l & 15, lk = l >> 4;
    int wv = t >> 6, jw = wv >> 2, hw = wv & 3;

    // ---- stage this hh-half's weights into LDS (once) ----
    {
        const uint4* sW = reinterpret_cast<const uint4*>(WpF + hh * 16384);
        const uint4* sW2 = reinterpret_cast<const uint4*>(W2F + hh * 8192);
        uint4* dW = reinterpret_cast<uint4*>(Wl);
        uint4* dW2 = reinterpret_cast<uint4*>(W2l);
        for (int q = t; q < 3072; q += 512) {
            if (q < 2048) dW[q] = sW[q];
            else dW2[q - 2048] = sW2[q - 2048];
        }
    }

    // ---- staging identity: thread t -> (row er, 16-col segment sg) ----
    int er = t >> 3, sg = t & 7;
    const float* sb = (sg < 4) ? plre : plim;
    int soff = (j0 + er) * 64 + (sg & 3) * 16;
    int colu = ((sg < 4) ? 0 : 64) + (sg & 3) * 16;
    int fw0 = FIDX(er, colu);
    int fw1 = FIDX(er, colu + 8);

    f32x4_t acc2[4][2];  // [dt][jt], accumulated over (a, ht)
#pragma unroll
    for (int dt = 0; dt < 4; ++dt)
#pragma unroll
        for (int jt = 0; jt < 2; ++jt) acc2[dt][jt] = (f32x4_t){0.f, 0.f, 0.f, 0.f};

    float4 s0, s1, s2, s3;
    {   // stage a0 into F2[0]
        const float* p = sb + (size_t)a0 * 65536 + soff;
        s0 = *reinterpret_cast<const float4*>(p);
        s1 = *reinterpret_cast<const float4*>(p + 4);
        s2 = *reinterpret_cast<const float4*>(p + 8);
        s3 = *reinterpret_cast<const float4*>(p + 12);
        *reinterpret_cast<uint4*>(&F2[0][fw0]) =
            make_uint4(pack2(s0.x, s0.y), pack2(s0.z, s0.w),
                       pack2(s1.x, s1.y), pack2(s1.z, s1.w));
        *reinterpret_cast<uint4*>(&F2[0][fw1]) =
            make_uint4(pack2(s2.x, s2.y), pack2(s2.z, s2.w),
                       pack2(s3.x, s3.y), pack2(s3.z, s3.w));
    }
    {   // prefetch a1
        const float* p = sb + (size_t)(a0 + 1) * 65536 + soff;
        s0 = *reinterpret_cast<const float4*>(p);
        s1 = *reinterpret_cast<const float4*>(p + 4);
        s2 = *reinterpret_cast<const float4*>(p + 8);
        s3 = *reinterpret_cast<const float4*>(p + 12);
    }
    __syncthreads();  // weights + F2[0] visible

    for (int ai = 0; ai < 8; ++ai) {
        int a = a0 + ai;
        int cur = ai & 1;
        const unsigned short* Fc = F2[cur];
        // ---- P emit (hh==0): P[e][ant] = re^2 + im^2 (fp16) ----
        if (hh == 0) {
            uint4 rr = *reinterpret_cast<const uint4*>(Fc + FIDX(er, sg * 8));
            uint4 ri = *reinterpret_cast<const uint4*>(Fc + FIDX(er, 64 + sg * 8));
            const unsigned short* pr = (const unsigned short*)&rr;
            const unsigned short* pi = (const unsigned short*)&ri;
            unsigned int pk[4];
#pragma unroll
            for (int i = 0; i < 4; ++i) {
                float re0 = __uint_as_float(((unsigned int)pr[2 * i]) << 16);
                float im0 = __uint_as_float(((unsigned int)pi[2 * i]) << 16);
                float re1 = __uint_as_float(((unsigned int)pr[2 * i + 1]) << 16);
                float im1 = __uint_as_float(((unsigned int)pi[2 * i + 1]) << 16);
                pk[i] = packh2(re0 * re0 + im0 * im0, re1 * re1 + im1 * im1);
            }
            *reinterpret_cast<uint4*>(&Pws[(unsigned)(a * 1024 + j0 + er) * 64 + sg * 8]) =
                make_uint4(pk[0], pk[1], pk[2], pk[3]);
        }
        // ---- layer 1 (swapped): D1T[h][j], wave tile 32h x 32j ----
        f32x4_t acc1[2][2];  // [ht][jt]
#pragma unroll
        for (int ht = 0; ht < 2; ++ht) {
            f32x4_t sa = *reinterpret_cast<const f32x4_t*>(
                Sa + a * H_DIM + hh * 128 + hw * 32 + ht * 16 + lk * 4);
            acc1[ht][0] = sa;
            acc1[ht][1] = sa;
        }
#pragma unroll
        for (int kc = 0; kc < 4; ++kc) {
            bf16x8_t aw0 = *reinterpret_cast<const bf16x8_t*>(
                Wl + (((hw * 2 + 0) * 4 + kc) << 9) + l * 8);
            bf16x8_t aw1 = *reinterpret_cast<const bf16x8_t*>(
                Wl + (((hw * 2 + 1) * 4 + kc) << 9) + l * 8);
            bf16x8_t bf0 = *reinterpret_cast<const bf16x8_t*>(
                Fc + FIDX(jw * 32 + lm, kc * 32 + lk * 8));
            bf16x8_t bf1 = *reinterpret_cast<const bf16x8_t*>(
                Fc + FIDX(jw * 32 + 16 + lm, kc * 32 + lk * 8));
            acc1[0][0] = __builtin_amdgcn_mfma_f32_16x16x32_bf16(aw0, bf0, acc1[0][0], 0, 0, 0);
            acc1[0][1] = __builtin_amdgcn_mfma_f32_16x16x32_bf16(aw0, bf1, acc1[0][1], 0, 0, 0);
            acc1[1][0] = __builtin_amdgcn_mfma_f32_16x16x32_bf16(aw1, bf0, acc1[1][0], 0, 0, 0);
            acc1[1][1] = __builtin_amdgcn_mfma_f32_16x16x32_bf16(aw1, bf1, acc1[1][1], 0, 0, 0);
        }
        // ---- layer 2: relu+cvt in-register, 16x16x16 MFMA, K=16 per ht ----
#pragma unroll
        for (int ht = 0; ht < 2; ++ht) {
            bf16x4_t hl0 = relu_cvt4(acc1[ht][0]);
            bf16x4_t hl1 = relu_cvt4(acc1[ht][1]);
#pragma unroll
            for (int dt = 0; dt < 4; ++dt) {
                bf16x4_t w2 = *reinterpret_cast<const bf16x4_t*>(
                    W2l + (((hw * 2 + ht) * 4 + dt) << 8) + l * 4);
                acc2[dt][0] = __builtin_amdgcn_mfma_f32_16x16x16bf16_1k(w2, hl0, acc2[dt][0], 0, 0, 0);
                acc2[dt][1] = __builtin_amdgcn_mfma_f32_16x16x16bf16_1k(w2, hl1, acc2[dt][1], 0, 0, 0);
            }
        }
        // ---- stage a+1 into the other buffer; ONE barrier per iter ----
        if (ai < 7) {
            *reinterpret_cast<uint4*>(&F2[cur ^ 1][fw0]) =
                make_uint4(pack2(s0.x, s0.y), pack2(s0.z, s0.w),
                           pack2(s1.x, s1.y), pack2(s1.z, s1.w));
            *reinterpret_cast<uint4*>(&F2[cur ^ 1][fw1]) =
                make_uint4(pack2(s2.x, s2.y), pack2(s2.z, s2.w),
                           pack2(s3.x, s3.y), pack2(s3.z, s3.w));
            if (ai < 6) {
                const float* p = sb + (size_t)(a0 + ai + 2) * 65536 + soff;
                s0 = *reinterpret_cast<const float4*>(p);
                s1 = *reinterpret_cast<const float4*>(p + 4);
                s2 = *reinterpret_cast<const float4*>(p + 8);
                s3 = *reinterpret_cast<const float4*>(p + 12);
            }
            __syncthreads();
        }
    }

    // ---- fold hw-partials via dead F2 buffer ([64 j][68 d] f32 = 17408B) ----
    float* R = reinterpret_cast<float*>(F2);
#define STORE_R()                                                              \
    do {                                                                       \
        _Pragma("unroll") for (int dt = 0; dt < 4; ++dt)                       \
            _Pragma("unroll") for (int jt = 0; jt < 2; ++jt)                   \
                *reinterpret_cast<f32x4_t*>(                                   \
                    &R[(jw * 32 + jt * 16 + lm) * 68 + dt * 16 + lk * 4]) =    \
                    acc2[dt][jt];                                              \
    } while (0)
#define ADD_R()                                                                \
    do {                                                                       \
        _Pragma("unroll") for (int dt = 0; dt < 4; ++dt)                       \
            _Pragma("unroll") for (int jt = 0; jt < 2; ++jt)                   \
                acc2[dt][jt] += *reinterpret_cast<const f32x4_t*>(             \
                    &R[(jw * 32 + jt * 16 + lm) * 68 + dt * 16 + lk * 4]);     \
    } while (0)
    __syncthreads();
    if (hw == 1) STORE_R();
    __syncthreads();
    if (hw == 0) ADD_R();
    __syncthreads();
    if (hw == 3) STORE_R();
    __syncthreads();
    if (hw == 2) ADD_R();
    __syncthreads();
    if (hw == 2) STORE_R();
    __syncthreads();
    if (hw == 0) {
        ADD_R();
#pragma unroll
        for (int dt = 0; dt < 4; ++dt)
#pragma unroll
            for (int jt = 0; jt < 2; ++jt)
                *reinterpret_cast<float4*>(
                    &partial[(size_t)(hh * 16 + ac) * 65536 +
                             (j0 + jw * 32 + jt * 16 + lm) * 64 + dt * 16 + lk * 4]) =
                    *reinterpret_cast<float4*>(&acc2[dt][jt]);
    }
#undef STORE_R
#undef ADD_R
}

// ---------------------------------------------------------------------------
// Kernel C: fused d-link MLP + per-AP normalization (R13 bulk-chunk-staged
// version — verified). One block per AP, 512 threads.
// ---------------------------------------------------------------------------
__global__ __launch_bounds__(512) void dlink_norm(
        const float* __restrict__ pv_re, const float* __restrict__ pv_im,
        const float* __restrict__ pldre, const float* __restrict__ pldim,
        const float* __restrict__ partial, const float* __restrict__ b2b,
        const float* __restrict__ W1a, const float* __restrict__ b1a,
        const float* __restrict__ W1b, const float* __restrict__ b1b,
        float* __restrict__ Q, float* __restrict__ out) {
    int a = blockIdx.x, t = threadIdx.x, w = t >> 6, l = t & 63;
    __shared__ float pvr[512], pvi[512], pldr[512], pldi[512];
    __shared__ float nrm[8][8];
    __shared__ __attribute__((aligned(16))) float feat[8][208];   // cols 193..207 = 0
    __shared__ __attribute__((aligned(16))) float h1[8][256];
    __shared__ __attribute__((aligned(16))) float o1[8][128];
    __shared__ __attribute__((aligned(16))) float Wbuf[4096];     // 16KB chunk buffer
    __shared__ float redn[8];
    __shared__ float SshInv;

    pvr[t] = pv_re[a * 512 + t];
    pvi[t] = pv_im[a * 512 + t];
    pldr[t] = pldre[a * 512 + t];
    pldi[t] = pldim[a * 512 + t];
    {   // mlp_ue_all for this AP's 8 rows
        float acc = 128.f * b2b[t & 63];
#pragma unroll
        for (int c = 0; c < 32; ++c) acc += partial[c * 65536 + a * 512 + t];
        feat[t >> 6][129 + (t & 63)] = acc;
    }
    if (t < 120) feat[t / 15][193 + t % 15] = 0.f;  // zero pad cols 193..207
    __syncthreads();
    feat[t >> 6][1 + (t & 63)] = pldr[t];
    feat[t >> 6][65 + (t & 63)] = pldi[t];
#pragma unroll
    for (int p = 0; p < 8; ++p) {
        int idx = w * 8 + p;
        int el = idx >> 3, u = idx & 7;
        float pr = pvr[u * 64 + l], pi = pvi[u * 64 + l];
        float qr = pldr[el * 64 + l], qi = pldi[el * 64 + l];
        float ir = pr * qr + pi * qi;   // conj(pv)*pl
        float ii = pr * qi - pi * qr;
        for (int m = 1; m < 64; m <<= 1) {
            ir += __shfl_xor(ir, m, 64);
            ii += __shfl_xor(ii, m, 64);
        }
        if (l == 0) nrm[el][u] = ir * ir + ii * ii;
    }
    __syncthreads();
    if (t < 8) {   // in_infer: exclude u == e % U == el
        float s = 0.f;
        for (int u = 0; u < 8; ++u)
            if (u != t) s += nrm[t][u];
        feat[t][0] = s;
    }
    __syncthreads();

    // ---- layer 1: 13 chunks of 16 k-rows (rows >=193 zeroed) ----
    {
        int p = w & 3, hv = w >> 2;
        int e0 = 2 * p, e1 = 2 * p + 1;
        const float* f0base = feat[e0];
        const float* f1base = feat[e1];
        float a00 = 0.f, a01 = 0.f, a10 = 0.f, a11 = 0.f;
        int row0 = t >> 6, col0 = (t & 63) * 4;
        int row1 = (t + 512) >> 6, col1 = col0;
        float4 pre0, pre1;
        {
            int g0 = row0, g1 = row1;
            pre0 = (g0 < 193) ? *reinterpret_cast<const float4*>(W1a + g0 * 256 + col0)
                              : make_float4(0.f, 0.f, 0.f, 0.f);
            pre1 = (g1 < 193) ? *reinterpret_cast<const float4*>(W1a + g1 * 256 + col1)
                              : make_float4(0.f, 0.f, 0.f, 0.f);
            *reinterpret_cast<float4*>(&Wbuf[row0 * 256 + col0]) = pre0;
            *reinterpret_cast<float4*>(&Wbuf[row1 * 256 + col1]) = pre1;
        }
        __syncthreads();
        for (int c = 0; c < 13; ++c) {
            if (c < 12) {
                int g0 = (c + 1) * 16 + row0, g1 = (c + 1) * 16 + row1;
                pre0 = (g0 < 193) ? *reinterpret_cast<const float4*>(W1a + g0 * 256 + col0)
                                  : make_float4(0.f, 0.f, 0.f, 0.f);
                pre1 = (g1 < 193) ? *reinterpret_cast<const float4*>(W1a + g1 * 256 + col1)
                                  : make_float4(0.f, 0.f, 0.f, 0.f);
            }
#pragma unroll
            for (int q = 0; q < 4; ++q) {
                float4 f0 = *reinterpret_cast<const float4*>(f0base + c * 16 + q * 4);
                float4 f1 = *reinterpret_cast<const float4*>(f1base + c * 16 + q * 4);
#pragma unroll
                for (int i = 0; i < 4; ++i) {
                    int kk = q * 4 + i;
                    float2 wv = *reinterpret_cast<const float2*>(&Wbuf[kk * 256 + hv * 128 + l * 2]);
                    float fi0 = (i == 0) ? f0.x : (i == 1) ? f0.y : (i == 2) ? f0.z : f0.w;
                    float fi1 = (i == 0) ? f1.x : (i == 1) ? f1.y : (i == 2) ? f1.z : f1.w;
                    a00 = fmaf(wv.x, fi0, a00);
                    a01 = fmaf(wv.y, fi0, a01);
                    a10 = fmaf(wv.x, fi1, a10);
                    a11 = fmaf(wv.y, fi1, a11);
                }
            }
            __syncthreads();
            if (c < 12) {
                *reinterpret_cast<float4*>(&Wbuf[row0 * 256 + col0]) = pre0;
                *reinterpret_cast<float4*>(&Wbuf[row1 * 256 + col1]) = pre1;
                __syncthreads();
            }
        }
        int h = hv * 128 + l * 2;
        float bb0 = b1a[h], bb1 = b1a[h + 1];
        float s00 = a00 + bb0, s01 = a01 + bb1, s10 = a10 + bb0, s11 = a11 + bb1;
        h1[e0][h] = s00 > 0.f ? s00 : 0.f;
        h1[e0][h + 1] = s01 > 0.f ? s01 : 0.f;
        h1[e1][h] = s10 > 0.f ? s10 : 0.f;
        h1[e1][h + 1] = s11 > 0.f ? s11 : 0.f;
    }
    __syncthreads();

    // ---- layer 2: 8 chunks of 32 k-rows of W1b[256][128] ----
    {
        int p = w & 3, cv = w >> 2;
        int e0 = 2 * p, e1 = 2 * p + 1;
        const float* g0base = h1[e0];
        const float* g1base = h1[e1];
        int c = cv * 64 + l;
        float a0 = 0.f, a1 = 0.f;
        int row0 = t >> 5, col0 = (t & 31) * 4;
        int row1 = (t + 512) >> 5, col1 = col0;
        float4 pre0, pre1;
        {
            pre0 = *reinterpret_cast<const float4*>(W1b + row0 * 128 + col0);
            pre1 = *reinterpret_cast<const float4*>(W1b + row1 * 128 + col1);
            *reinterpret_cast<float4*>(&Wbuf[row0 * 128 + col0]) = pre0;
            *reinterpret_cast<float4*>(&Wbuf[row1 * 128 + col1]) = pre1;
        }
        __syncthreads();
        for (int ch = 0; ch < 8; ++ch) {
            if (ch < 7) {
                const float* src = W1b + (ch + 1) * 32 * 128;
                pre0 = *reinterpret_cast<const float4*>(src + row0 * 128 + col0);
                pre1 = *reinterpret_cast<const float4*>(src + row1 * 128 + col1);
            }
#pragma unroll
            for (int q = 0; q < 8; ++q) {
                float4 g0 = *reinterpret_cast<const float4*>(g0base + ch * 32 + q * 4);
                float4 g1 = *reinterpret_cast<const float4*>(g1base + ch * 32 + q * 4);
#pragma unroll
                for (int i = 0; i < 4; ++i) {
                    int kk = q * 4 + i;
                    float wv = Wbuf[kk * 128 + c];
                    float gi0 = (i == 0) ? g0.x : (i == 1) ? g0.y : (i == 2) ? g0.z : g0.w;
                    float gi1 = (i == 0) ? g1.x : (i == 1) ? g1.y : (i == 2) ? g1.z : g1.w;
                    a0 = fmaf(wv, gi0, a0);
                    a1 = fmaf(wv, gi1, a1);
                }
            }
            __syncthreads();
            if (ch < 7) {
                *reinterpret_cast<float4*>(&Wbuf[row0 * 128 + col0]) = pre0;
                *reinterpret_cast<float4*>(&Wbuf[row1 * 128 + col1]) = pre1;
                __syncthreads();
            }
        }
        float bb = b1b[c];
        o1[e0][c] = bb + a0;
        o1[e1][c] = bb + a1;
    }
    __syncthreads();

    // ---- normalization ----
    {
        int el = t >> 6, ant = t & 63;
        float re = o1[el][ant], im = o1[el][64 + ant];
        float v = sqrtf(re * re + im * im);
        for (int m = 1; m < 64; m <<= 1) v += __shfl_xor(v, m, 64);
        if (l == 0) redn[w] = v;
    }
    __syncthreads();
    if (t == 0) {
        float S = redn[0] + redn[1] + redn[2] + redn[3] +
                  redn[4] + redn[5] + redn[6] + redn[7];
        SshInv = 1.f / S;
    }
    __syncthreads();
    {
        float inv = SshInv;
        int el = t >> 6, ant = t & 63;
        out[a * 512 + t] = o1[el][ant] * inv;
        out[65536 + a * 512 + t] = o1[el][64 + ant] * inv;
        if (t < 64) {   // Q = |sum_u pv_new|^2
            float sr = 0.f, si = 0.f;
#pragma unroll
            for (int u = 0; u < 8; ++u) {
                sr += o1[u][t];
                si += o1[u][64 + t];
            }
            sr *= inv;
            si *= inv;
            Q[a * 64 + t] = sr * sr + si * si;
        }
    }
}

// ---------------------------------------------------------------------------
// Kernel D: final aggregate from fp16 P (16.8 MB). One wave per j.
// ---------------------------------------------------------------------------
__global__ __launch_bounds__(256) void final_agg(const unsigned short* __restrict__ Pws,
                                                 const float* __restrict__ Qv,
                                                 float* __restrict__ out) {
    int bid = blockIdx.x, t = threadIdx.x, w = t >> 6, l = t & 63;
    __shared__ __attribute__((aligned(16))) float Qc[128][68];
    for (int i = t; i < 8192; i += 256) Qc[i >> 6][i & 63] = Qv[i];
    __syncthreads();
    int j = bid * 4 + w;
    int as = l >> 3, og = l & 7;
    float acc = 0.f;
#pragma unroll 4
    for (int ab = 0; ab < 16; ++ab) {
        int aa = ab * 8 + as;
        uint4 pv4 = *reinterpret_cast<const uint4*>(&Pws[(unsigned)(aa * 1024 + j) * 64 + og * 8]);
        float4 q0 = *reinterpret_cast<const float4*>(&Qc[aa][og * 8]);
        float4 q1 = *reinterpret_cast<const float4*>(&Qc[aa][og * 8 + 4]);
        const unsigned short* hp = (const unsigned short*)&pv4;
        acc += __half2float(__ushort_as_half(hp[0])) * q0.x;
        acc += __half2float(__ushort_as_half(hp[1])) * q0.y;
        acc += __half2float(__ushort_as_half(hp[2])) * q0.z;
        acc += __half2float(__ushort_as_half(hp[3])) * q0.w;
        acc += __half2float(__ushort_as_half(hp[4])) * q1.x;
        acc += __half2float(__ushort_as_half(hp[5])) * q1.y;
        acc += __half2float(__ushort_as_half(hp[6])) * q1.z;
        acc += __half2float(__ushort_as_half(hp[7])) * q1.w;
    }
    for (int m = 1; m < 64; m <<= 1) acc += __shfl_xor(acc, m, 64);
    if (l == 0) out[131072 + j] = acc;
}

extern "C" void kernel_launch(void* const* d_in, const int* in_sizes, int n_in,
                              void* d_out, int out_size, void* d_ws, size_t ws_size,
                              hipStream_t stream) {
    const float* plre = (const float*)d_in[0];
    const float* plim = (const float*)d_in[1];
    const float* pldre = (const float*)d_in[2];
    const float* pldim = (const float*)d_in[3];
    const float* pvre = (const float*)d_in[4];
    const float* pvim = (const float*)d_in[5];
    const float* W2a = (const float*)d_in[6];
    const float* b2a = (const float*)d_in[7];
    const float* W2b = (const float*)d_in[8];
    const float* b2b = (const float*)d_in[9];
    const float* W1a = (const float*)d_in[10];
    const float* b1a = (const float*)d_in[11];
    const float* W1b = (const float*)d_in[12];
    const float* b1b = (const float*)d_in[13];

    char* ws = (char*)d_ws;
    float* Sa = (float*)(ws);                               // 131072 B
    unsigned short* WpF = (unsigned short*)(ws + 131072);   // 65536 B
    unsigned short* W2F = (unsigned short*)(ws + 196608);   // 32768 B
    float* Q = (float*)(ws + 229376);                       // 32768 B
    float* partial = (float*)(ws + 262144);                 // 8388608 B (32 chunks)
    unsigned short* Pws = (unsigned short*)(ws + 8650752);  // 16777216 B
    float* out = (float*)d_out;

    prep_kernel<<<256, 256, 0, stream>>>(pvre, pvim, W2a, b2a, W2b, Sa, WpF, W2F);
    mlp2_kernel<<<512, 512, 0, stream>>>(plre, plim, Sa, WpF, W2F, partial, Pws);
    dlink_norm<<<128, 512, 0, stream>>>(pvre, pvim, pldre, pldim, partial, b2b,
                                        W1a, b1a, W1b, b1b, Q, out);
    final_agg<<<256, 256, 0, stream>>>(Pws, Q, out);
}

// Round 16
// 65.177 us; speedup vs baseline: 1.3792x; 1.0007x over previous
//
#include <hip/hip_runtime.h>
#include <hip/hip_bf16.h>
#include <hip/hip_fp16.h>

#define A_NUM 128
#define U_NUM 8
#define ANT 64
#define D2 64
#define H_DIM 256
#define NUE 1024
#define E_INT 131072

typedef __attribute__((ext_vector_type(8))) short bf16x8_t;
typedef __attribute__((ext_vector_type(4))) short bf16x4_t;
typedef __attribute__((ext_vector_type(4))) float f32x4_t;

// round-to-nearest-even f32 -> bf16
static __device__ inline unsigned short f2bf(float x) {
    unsigned int u = __float_as_uint(x);
    unsigned int r = (u + 0x7fffu + ((u >> 16) & 1u)) >> 16;
    return (unsigned short)r;
}
static __device__ inline unsigned int pack2(float a, float b) {
    return (unsigned int)f2bf(a) | ((unsigned int)f2bf(b) << 16);
}
static __device__ inline unsigned int packh2(float a, float b) {
    return (unsigned int)__half_as_ushort(__float2half(a)) |
           ((unsigned int)__half_as_ushort(__float2half(b)) << 16);
}
// relu + cvt to l2 B-frag (k = lk*4 + i matches rows r of l1T output)
static __device__ inline bf16x4_t relu_cvt4(f32x4_t v) {
    float t0 = v[0] > 0.f ? v[0] : 0.f;
    float t1 = v[1] > 0.f ? v[1] : 0.f;
    float t2 = v[2] > 0.f ? v[2] : 0.f;
    float t3 = v[3] > 0.f ? v[3] : 0.f;
    union { unsigned int u[2]; bf16x4_t s; } r;
    r.u[0] = pack2(t0, t1);
    r.u[1] = pack2(t2, t3);
    return r.s;
}

// swizzled index into an unpadded [64][128] u16 tile: spreads the 16-way
// row-bank alias (256B rows) into free 2-way. 8-aligned col groups stay
// contiguous under the XOR (key touches bits 3-5 only).
#define FIDX(r, c) (((r) << 7) + ((c) ^ (((r) & 7) << 3)))

// ---------------------------------------------------------------------------
// Kernel A: prep. blocks 0..127: Sa[a,h]. blocks 128..255: fragment-order
// bf16 weight packs WpF (l1 A-frags) / W2F (l2 A-frags, K=16 layout).
// ---------------------------------------------------------------------------
__global__ void prep_kernel(const float* __restrict__ pv_re, const float* __restrict__ pv_im,
                            const float* __restrict__ W2a, const float* __restrict__ b2a,
                            const float* __restrict__ W2b,
                            float* __restrict__ Sa, unsigned short* __restrict__ WpF,
                            unsigned short* __restrict__ W2F) {
    int bid = blockIdx.x, t = threadIdx.x;
    if (bid < A_NUM) {
        __shared__ float sre[ANT], sim[ANT];
        if (t < ANT) {
            float s = 0.f;
            for (int u = 0; u < U_NUM; ++u) s += pv_re[bid * 512 + u * 64 + t];
            sre[t] = s;
        } else if (t < 2 * ANT) {
            int ant = t - ANT;
            float s = 0.f;
            for (int u = 0; u < U_NUM; ++u) s += pv_im[bid * 512 + u * 64 + ant];
            sim[ant] = s;
        }
        __syncthreads();
        float a0 = 0.f, a1 = 0.f, a2 = 0.f, a3 = 0.f;
        for (int ant = 0; ant < ANT; ant += 2) {
            a0 += sre[ant] * W2a[(64 + ant) * H_DIM + t];
            a1 += sim[ant] * W2a[(192 + ant) * H_DIM + t];
            a2 += sre[ant + 1] * W2a[(64 + ant + 1) * H_DIM + t];
            a3 += sim[ant + 1] * W2a[(192 + ant + 1) * H_DIM + t];
        }
        Sa[bid * H_DIM + t] = b2a[t] + ((a0 + a2) + (a1 + a3));
    } else {
        for (int f = (bid - A_NUM) * 256 + t; f < 32768 + 16384; f += 128 * 256) {
            if (f < 32768) {  // WpF (l1 A-frags, K=32 layout)
                int i = f & 7, lml = (f >> 3) & 15, lkl = (f >> 7) & 3;
                int kc = (f >> 9) & 3, ht8 = (f >> 11) & 7, hh = (f >> 14) & 1;
                int h = hh * 128 + ht8 * 16 + lml;
                int k = kc * 32 + lkl * 8 + i;
                int row = (k < 64) ? k : (k + 64);
                WpF[f] = f2bf(W2a[row * H_DIM + h]);
            } else {          // W2F (l2 A-frags, K=16 layout)
                int f2 = f - 32768;
                int i = f2 & 3, ll = (f2 >> 2) & 63;
                int dt = (f2 >> 8) & 3, ht8 = (f2 >> 10) & 7, hh = (f2 >> 13) & 1;
                int d = dt * 16 + (ll & 15);
                int k = hh * 128 + ht8 * 16 + (ll >> 4) * 4 + i;
                W2F[f2] = f2bf(W2b[k * D2 + d]);
            }
        }
    }
}

// ---------------------------------------------------------------------------
// Kernel B: big edge MLP (R14 geometry + w2 register hoist + in-register
// P-emit at stage time). Grid 512 = 16 jt(64j) x 2 hh x 16 ac, 512 thr
// (8 waves = 2 jw x 4 hw), 2 blocks/CU (80KB LDS). ONE barrier per a-iter.
// Staging pairs re+im of the same 8 columns per thread so P = re^2+im^2 is
// computed from f32 registers (no LDS round trip for P).
// ---------------------------------------------------------------------------
__global__ __launch_bounds__(512) void mlp2_kernel(
        const float* __restrict__ plre, const float* __restrict__ plim,
        const float* __restrict__ Sa, const unsigned short* __restrict__ WpF,
        const unsigned short* __restrict__ W2F, float* __restrict__ partial,
        unsigned short* __restrict__ Pws) {
    __shared__ __attribute__((aligned(16))) unsigned short Wl[16384];    // 32KB
    __shared__ __attribute__((aligned(16))) unsigned short W2l[8192];    // 16KB
    __shared__ __attribute__((aligned(16))) unsigned short F2[2][8192];  // 32KB swz [64][128]
    int bid = blockIdx.x;
    int ac = bid >> 5, hh = (bid >> 4) & 1, jtile = bid & 15;
    int j0 = jtile * 64, a0 = ac * 8;
    int t = threadIdx.x, l = t & 63, lm = l & 15, lk = l >> 4;
    int wv = t >> 6, jw = wv >> 2, hw = wv & 3;

    // ---- stage this hh-half's weights into LDS (once) ----
    {
        const uint4* sW = reinterpret_cast<const uint4*>(WpF + hh * 16384);
        const uint4* sW2 = reinterpret_cast<const uint4*>(W2F + hh * 8192);
        uint4* dW = reinterpret_cast<uint4*>(Wl);
        uint4* dW2 = reinterpret_cast<uint4*>(W2l);
        for (int q = t; q < 3072; q += 512) {
            if (q < 2048) dW[q] = sW[q];
            else dW2[q - 2048] = sW2[q - 2048];
        }
    }

    // ---- staging identity: thread t -> (row er, 8-col group sg), re+im ----
    int er = t >> 3, sg = t & 7;
    int soff = (j0 + er) * 64 + sg * 8;
    int fwRe = FIDX(er, sg * 8);
    int fwIm = FIDX(er, 64 + sg * 8);

    f32x4_t acc2[4][2];  // [dt][jt], accumulated over (a, ht)
#pragma unroll
    for (int dt = 0; dt < 4; ++dt)
#pragma unroll
        for (int jt = 0; jt < 2; ++jt) acc2[dt][jt] = (f32x4_t){0.f, 0.f, 0.f, 0.f};

    float4 r0, r1, i0, i1;
    {   // stage a0 into F2[0] + in-register P emit for a0
        const float* pr = plre + (size_t)a0 * 65536 + soff;
        const float* pi = plim + (size_t)a0 * 65536 + soff;
        r0 = *reinterpret_cast<const float4*>(pr);
        r1 = *reinterpret_cast<const float4*>(pr + 4);
        i0 = *reinterpret_cast<const float4*>(pi);
        i1 = *reinterpret_cast<const float4*>(pi + 4);
        *reinterpret_cast<uint4*>(&F2[0][fwRe]) =
            make_uint4(pack2(r0.x, r0.y), pack2(r0.z, r0.w),
                       pack2(r1.x, r1.y), pack2(r1.z, r1.w));
        *reinterpret_cast<uint4*>(&F2[0][fwIm]) =
            make_uint4(pack2(i0.x, i0.y), pack2(i0.z, i0.w),
                       pack2(i1.x, i1.y), pack2(i1.z, i1.w));
        if (hh == 0) {
            *reinterpret_cast<uint4*>(&Pws[(unsigned)(a0 * 1024 + j0 + er) * 64 + sg * 8]) =
                make_uint4(packh2(r0.x * r0.x + i0.x * i0.x, r0.y * r0.y + i0.y * i0.y),
                           packh2(r0.z * r0.z + i0.z * i0.z, r0.w * r0.w + i0.w * i0.w),
                           packh2(r1.x * r1.x + i1.x * i1.x, r1.y * r1.y + i1.y * i1.y),
                           packh2(r1.z * r1.z + i1.z * i1.z, r1.w * r1.w + i1.w * i1.w));
        }
    }
    {   // prefetch a1
        const float* pr = plre + (size_t)(a0 + 1) * 65536 + soff;
        const float* pi = plim + (size_t)(a0 + 1) * 65536 + soff;
        r0 = *reinterpret_cast<const float4*>(pr);
        r1 = *reinterpret_cast<const float4*>(pr + 4);
        i0 = *reinterpret_cast<const float4*>(pi);
        i1 = *reinterpret_cast<const float4*>(pi + 4);
    }
    __syncthreads();  // weights + F2[0] visible

    // ---- hoist l2 weight fragments into registers (loop-invariant) ----
    bf16x4_t w2h[2][4];
#pragma unroll
    for (int ht = 0; ht < 2; ++ht)
#pragma unroll
        for (int dt = 0; dt < 4; ++dt)
            w2h[ht][dt] = *reinterpret_cast<const bf16x4_t*>(
                W2l + (((hw * 2 + ht) * 4 + dt) << 8) + l * 4);

    for (int ai = 0; ai < 8; ++ai) {
        int a = a0 + ai;
        int cur = ai & 1;
        const unsigned short* Fc = F2[cur];
        // ---- layer 1 (swapped): D1T[h][j], wave tile 32h x 32j ----
        f32x4_t acc1[2][2];  // [ht][jt]
#pragma unroll
        for (int ht = 0; ht < 2; ++ht) {
            f32x4_t sa = *reinterpret_cast<const f32x4_t*>(
                Sa + a * H_DIM + hh * 128 + hw * 32 + ht * 16 + lk * 4);
            acc1[ht][0] = sa;
            acc1[ht][1] = sa;
        }
#pragma unroll
        for (int kc = 0; kc < 4; ++kc) {
            bf16x8_t aw0 = *reinterpret_cast<const bf16x8_t*>(
                Wl + (((hw * 2 + 0) * 4 + kc) << 9) + l * 8);
            bf16x8_t aw1 = *reinterpret_cast<const bf16x8_t*>(
                Wl + (((hw * 2 + 1) * 4 + kc) << 9) + l * 8);
            bf16x8_t bf0 = *reinterpret_cast<const bf16x8_t*>(
                Fc + FIDX(jw * 32 + lm, kc * 32 + lk * 8));
            bf16x8_t bf1 = *reinterpret_cast<const bf16x8_t*>(
                Fc + FIDX(jw * 32 + 16 + lm, kc * 32 + lk * 8));
            acc1[0][0] = __builtin_amdgcn_mfma_f32_16x16x32_bf16(aw0, bf0, acc1[0][0], 0, 0, 0);
            acc1[0][1] = __builtin_amdgcn_mfma_f32_16x16x32_bf16(aw0, bf1, acc1[0][1], 0, 0, 0);
            acc1[1][0] = __builtin_amdgcn_mfma_f32_16x16x32_bf16(aw1, bf0, acc1[1][0], 0, 0, 0);
            acc1[1][1] = __builtin_amdgcn_mfma_f32_16x16x32_bf16(aw1, bf1, acc1[1][1], 0, 0, 0);
        }
        // ---- layer 2: relu+cvt in-register, 16x16x16 MFMA, K=16 per ht ----
#pragma unroll
        for (int ht = 0; ht < 2; ++ht) {
            bf16x4_t hl0 = relu_cvt4(acc1[ht][0]);
            bf16x4_t hl1 = relu_cvt4(acc1[ht][1]);
#pragma unroll
            for (int dt = 0; dt < 4; ++dt) {
                acc2[dt][0] = __builtin_amdgcn_mfma_f32_16x16x16bf16_1k(w2h[ht][dt], hl0, acc2[dt][0], 0, 0, 0);
                acc2[dt][1] = __builtin_amdgcn_mfma_f32_16x16x16bf16_1k(w2h[ht][dt], hl1, acc2[dt][1], 0, 0, 0);
            }
        }
        // ---- stage a+1 into the other buffer (+ in-register P emit) ----
        if (ai < 7) {
            int an = a + 1;
            *reinterpret_cast<uint4*>(&F2[cur ^ 1][fwRe]) =
                make_uint4(pack2(r0.x, r0.y), pack2(r0.z, r0.w),
                           pack2(r1.x, r1.y), pack2(r1.z, r1.w));
            *reinterpret_cast<uint4*>(&F2[cur ^ 1][fwIm]) =
                make_uint4(pack2(i0.x, i0.y), pack2(i0.z, i0.w),
                           pack2(i1.x, i1.y), pack2(i1.z, i1.w));
            if (hh == 0) {
                *reinterpret_cast<uint4*>(&Pws[(unsigned)(an * 1024 + j0 + er) * 64 + sg * 8]) =
                    make_uint4(packh2(r0.x * r0.x + i0.x * i0.x, r0.y * r0.y + i0.y * i0.y),
                               packh2(r0.z * r0.z + i0.z * i0.z, r0.w * r0.w + i0.w * i0.w),
                               packh2(r1.x * r1.x + i1.x * i1.x, r1.y * r1.y + i1.y * i1.y),
                               packh2(r1.z * r1.z + i1.z * i1.z, r1.w * r1.w + i1.w * i1.w));
            }
            if (ai < 6) {
                const float* pr = plre + (size_t)(a0 + ai + 2) * 65536 + soff;
                const float* pi = plim + (size_t)(a0 + ai + 2) * 65536 + soff;
                r0 = *reinterpret_cast<const float4*>(pr);
                r1 = *reinterpret_cast<const float4*>(pr + 4);
                i0 = *reinterpret_cast<const float4*>(pi);
                i1 = *reinterpret_cast<const float4*>(pi + 4);
            }
            __syncthreads();
        }
    }

    // ---- fold hw-partials via dead F2 buffer ([64 j][68 d] f32 = 17408B) ----
    float* R = reinterpret_cast<float*>(F2);
#define STORE_R()                                                              \
    do {                                                                       \
        _Pragma("unroll") for (int dt = 0; dt < 4; ++dt)                       \
            _Pragma("unroll") for (int jt = 0; jt < 2; ++jt)                   \
                *reinterpret_cast<f32x4_t*>(                                   \
                    &R[(jw * 32 + jt * 16 + lm) * 68 + dt * 16 + lk * 4]) =    \
                    acc2[dt][jt];                                              \
    } while (0)
#define ADD_R()                                                                \
    do {                                                                       \
        _Pragma("unroll") for (int dt = 0; dt < 4; ++dt)                       \
            _Pragma("unroll") for (int jt = 0; jt < 2; ++jt)                   \
                acc2[dt][jt] += *reinterpret_cast<const f32x4_t*>(             \
                    &R[(jw * 32 + jt * 16 + lm) * 68 + dt * 16 + lk * 4]);     \
    } while (0)
    __syncthreads();
    if (hw == 1) STORE_R();
    __syncthreads();
    if (hw == 0) ADD_R();
    __syncthreads();
    if (hw == 3) STORE_R();
    __syncthreads();
    if (hw == 2) ADD_R();
    __syncthreads();
    if (hw == 2) STORE_R();
    __syncthreads();
    if (hw == 0) {
        ADD_R();
#pragma unroll
        for (int dt = 0; dt < 4; ++dt)
#pragma unroll
            for (int jt = 0; jt < 2; ++jt)
                *reinterpret_cast<float4*>(
                    &partial[(size_t)(hh * 16 + ac) * 65536 +
                             (j0 + jw * 32 + jt * 16 + lm) * 64 + dt * 16 + lk * 4]) =
                    *reinterpret_cast<float4*>(&acc2[dt][jt]);
    }
#undef STORE_R
#undef ADD_R
}

// ---------------------------------------------------------------------------
// Kernel C: fused d-link MLP + per-AP normalization (R13 bulk-chunk-staged
// version — verified). One block per AP, 512 threads.
// ---------------------------------------------------------------------------
__global__ __launch_bounds__(512) void dlink_norm(
        const float* __restrict__ pv_re, const float* __restrict__ pv_im,
        const float* __restrict__ pldre, const float* __restrict__ pldim,
        const float* __restrict__ partial, const float* __restrict__ b2b,
        const float* __restrict__ W1a, const float* __restrict__ b1a,
        const float* __restrict__ W1b, const float* __restrict__ b1b,
        float* __restrict__ Q, float* __restrict__ out) {
    int a = blockIdx.x, t = threadIdx.x, w = t >> 6, l = t & 63;
    __shared__ float pvr[512], pvi[512], pldr[512], pldi[512];
    __shared__ float nrm[8][8];
    __shared__ __attribute__((aligned(16))) float feat[8][208];   // cols 193..207 = 0
    __shared__ __attribute__((aligned(16))) float h1[8][256];
    __shared__ __attribute__((aligned(16))) float o1[8][128];
    __shared__ __attribute__((aligned(16))) float Wbuf[4096];     // 16KB chunk buffer
    __shared__ float redn[8];
    __shared__ float SshInv;

    pvr[t] = pv_re[a * 512 + t];
    pvi[t] = pv_im[a * 512 + t];
    pldr[t] = pldre[a * 512 + t];
    pldi[t] = pldim[a * 512 + t];
    {   // mlp_ue_all for this AP's 8 rows
        float acc = 128.f * b2b[t & 63];
#pragma unroll
        for (int c = 0; c < 32; ++c) acc += partial[c * 65536 + a * 512 + t];
        feat[t >> 6][129 + (t & 63)] = acc;
    }
    if (t < 120) feat[t / 15][193 + t % 15] = 0.f;  // zero pad cols 193..207
    __syncthreads();
    feat[t >> 6][1 + (t & 63)] = pldr[t];
    feat[t >> 6][65 + (t & 63)] = pldi[t];
#pragma unroll
    for (int p = 0; p < 8; ++p) {
        int idx = w * 8 + p;
        int el = idx >> 3, u = idx & 7;
        float pr = pvr[u * 64 + l], pi = pvi[u * 64 + l];
        float qr = pldr[el * 64 + l], qi = pldi[el * 64 + l];
        float ir = pr * qr + pi * qi;   // conj(pv)*pl
        float ii = pr * qi - pi * qr;
        for (int m = 1; m < 64; m <<= 1) {
            ir += __shfl_xor(ir, m, 64);
            ii += __shfl_xor(ii, m, 64);
        }
        if (l == 0) nrm[el][u] = ir * ir + ii * ii;
    }
    __syncthreads();
    if (t < 8) {   // in_infer: exclude u == e % U == el
        float s = 0.f;
        for (int u = 0; u < 8; ++u)
            if (u != t) s += nrm[t][u];
        feat[t][0] = s;
    }
    __syncthreads();

    // ---- layer 1: 13 chunks of 16 k-rows (rows >=193 zeroed) ----
    {
        int p = w & 3, hv = w >> 2;
        int e0 = 2 * p, e1 = 2 * p + 1;
        const float* f0base = feat[e0];
        const float* f1base = feat[e1];
        float a00 = 0.f, a01 = 0.f, a10 = 0.f, a11 = 0.f;
        int row0 = t >> 6, col0 = (t & 63) * 4;
        int row1 = (t + 512) >> 6, col1 = col0;
        float4 pre0, pre1;
        {
            int g0 = row0, g1 = row1;
            pre0 = (g0 < 193) ? *reinterpret_cast<const float4*>(W1a + g0 * 256 + col0)
                              : make_float4(0.f, 0.f, 0.f, 0.f);
            pre1 = (g1 < 193) ? *reinterpret_cast<const float4*>(W1a + g1 * 256 + col1)
                              : make_float4(0.f, 0.f, 0.f, 0.f);
            *reinterpret_cast<float4*>(&Wbuf[row0 * 256 + col0]) = pre0;
            *reinterpret_cast<float4*>(&Wbuf[row1 * 256 + col1]) = pre1;
        }
        __syncthreads();
        for (int c = 0; c < 13; ++c) {
            if (c < 12) {
                int g0 = (c + 1) * 16 + row0, g1 = (c + 1) * 16 + row1;
                pre0 = (g0 < 193) ? *reinterpret_cast<const float4*>(W1a + g0 * 256 + col0)
                                  : make_float4(0.f, 0.f, 0.f, 0.f);
                pre1 = (g1 < 193) ? *reinterpret_cast<const float4*>(W1a + g1 * 256 + col1)
                                  : make_float4(0.f, 0.f, 0.f, 0.f);
            }
#pragma unroll
            for (int q = 0; q < 4; ++q) {
                float4 f0 = *reinterpret_cast<const float4*>(f0base + c * 16 + q * 4);
                float4 f1 = *reinterpret_cast<const float4*>(f1base + c * 16 + q * 4);
#pragma unroll
                for (int i = 0; i < 4; ++i) {
                    int kk = q * 4 + i;
                    float2 wv = *reinterpret_cast<const float2*>(&Wbuf[kk * 256 + hv * 128 + l * 2]);
                    float fi0 = (i == 0) ? f0.x : (i == 1) ? f0.y : (i == 2) ? f0.z : f0.w;
                    float fi1 = (i == 0) ? f1.x : (i == 1) ? f1.y : (i == 2) ? f1.z : f1.w;
                    a00 = fmaf(wv.x, fi0, a00);
                    a01 = fmaf(wv.y, fi0, a01);
                    a10 = fmaf(wv.x, fi1, a10);
                    a11 = fmaf(wv.y, fi1, a11);
                }
            }
            __syncthreads();
            if (c < 12) {
                *reinterpret_cast<float4*>(&Wbuf[row0 * 256 + col0]) = pre0;
                *reinterpret_cast<float4*>(&Wbuf[row1 * 256 + col1]) = pre1;
                __syncthreads();
            }
        }
        int h = hv * 128 + l * 2;
        float bb0 = b1a[h], bb1 = b1a[h + 1];
        float s00 = a00 + bb0, s01 = a01 + bb1, s10 = a10 + bb0, s11 = a11 + bb1;
        h1[e0][h] = s00 > 0.f ? s00 : 0.f;
        h1[e0][h + 1] = s01 > 0.f ? s01 : 0.f;
        h1[e1][h] = s10 > 0.f ? s10 : 0.f;
        h1[e1][h + 1] = s11 > 0.f ? s11 : 0.f;
    }
    __syncthreads();

    // ---- layer 2: 8 chunks of 32 k-rows of W1b[256][128] ----
    {
        int p = w & 3, cv = w >> 2;
        int e0 = 2 * p, e1 = 2 * p + 1;
        const float* g0base = h1[e0];
        const float* g1base = h1[e1];
        int c = cv * 64 + l;
        float a0 = 0.f, a1 = 0.f;
        int row0 = t >> 5, col0 = (t & 31) * 4;
        int row1 = (t + 512) >> 5, col1 = col0;
        float4 pre0, pre1;
        {
            pre0 = *reinterpret_cast<const float4*>(W1b + row0 * 128 + col0);
            pre1 = *reinterpret_cast<const float4*>(W1b + row1 * 128 + col1);
            *reinterpret_cast<float4*>(&Wbuf[row0 * 128 + col0]) = pre0;
            *reinterpret_cast<float4*>(&Wbuf[row1 * 128 + col1]) = pre1;
        }
        __syncthreads();
        for (int ch = 0; ch < 8; ++ch) {
            if (ch < 7) {
                const float* src = W1b + (ch + 1) * 32 * 128;
                pre0 = *reinterpret_cast<const float4*>(src + row0 * 128 + col0);
                pre1 = *reinterpret_cast<const float4*>(src + row1 * 128 + col1);
            }
#pragma unroll
            for (int q = 0; q < 8; ++q) {
                float4 g0 = *reinterpret_cast<const float4*>(g0base + ch * 32 + q * 4);
                float4 g1 = *reinterpret_cast<const float4*>(g1base + ch * 32 + q * 4);
#pragma unroll
                for (int i = 0; i < 4; ++i) {
                    int kk = q * 4 + i;
                    float wv = Wbuf[kk * 128 + c];
                    float gi0 = (i == 0) ? g0.x : (i == 1) ? g0.y : (i == 2) ? g0.z : g0.w;
                    float gi1 = (i == 0) ? g1.x : (i == 1) ? g1.y : (i == 2) ? g1.z : g1.w;
                    a0 = fmaf(wv, gi0, a0);
                    a1 = fmaf(wv, gi1, a1);
                }
            }
            __syncthreads();
            if (ch < 7) {
                *reinterpret_cast<float4*>(&Wbuf[row0 * 128 + col0]) = pre0;
                *reinterpret_cast<float4*>(&Wbuf[row1 * 128 + col1]) = pre1;
                __syncthreads();
            }
        }
        float bb = b1b[c];
        o1[e0][c] = bb + a0;
        o1[e1][c] = bb + a1;
    }
    __syncthreads();

    // ---- normalization ----
    {
        int el = t >> 6, ant = t & 63;
        float re = o1[el][ant], im = o1[el][64 + ant];
        float v = sqrtf(re * re + im * im);
        for (int m = 1; m < 64; m <<= 1) v += __shfl_xor(v, m, 64);
        if (l == 0) redn[w] = v;
    }
    __syncthreads();
    if (t == 0) {
        float S = redn[0] + redn[1] + redn[2] + redn[3] +
                  redn[4] + redn[5] + redn[6] + redn[7];
        SshInv = 1.f / S;
    }
    __syncthreads();
    {
        float inv = SshInv;
        int el = t >> 6, ant = t & 63;
        out[a * 512 + t] = o1[el][ant] * inv;
        out[65536 + a * 512 + t] = o1[el][64 + ant] * inv;
        if (t < 64) {   // Q = |sum_u pv_new|^2
            float sr = 0.f, si = 0.f;
#pragma unroll
            for (int u = 0; u < 8; ++u) {
                sr += o1[u][t];
                si += o1[u][64 + t];
            }
            sr *= inv;
            si *= inv;
            Q[a * 64 + t] = sr * sr + si * si;
        }
    }
}

// ---------------------------------------------------------------------------
// Kernel D: final aggregate from fp16 P (16.8 MB). One wave per j.
// ---------------------------------------------------------------------------
__global__ __launch_bounds__(256) void final_agg(const unsigned short* __restrict__ Pws,
                                                 const float* __restrict__ Qv,
                                                 float* __restrict__ out) {
    int bid = blockIdx.x, t = threadIdx.x, w = t >> 6, l = t & 63;
    __shared__ __attribute__((aligned(16))) float Qc[128][68];
    for (int i = t; i < 8192; i += 256) Qc[i >> 6][i & 63] = Qv[i];
    __syncthreads();
    int j = bid * 4 + w;
    int as = l >> 3, og = l & 7;
    float acc = 0.f;
#pragma unroll 4
    for (int ab = 0; ab < 16; ++ab) {
        int aa = ab * 8 + as;
        uint4 pv4 = *reinterpret_cast<const uint4*>(&Pws[(unsigned)(aa * 1024 + j) * 64 + og * 8]);
        float4 q0 = *reinterpret_cast<const float4*>(&Qc[aa][og * 8]);
        float4 q1 = *reinterpret_cast<const float4*>(&Qc[aa][og * 8 + 4]);
        const unsigned short* hp = (const unsigned short*)&pv4;
        acc += __half2float(__ushort_as_half(hp[0])) * q0.x;
        acc += __half2float(__ushort_as_half(hp[1])) * q0.y;
        acc += __half2float(__ushort_as_half(hp[2])) * q0.z;
        acc += __half2float(__ushort_as_half(hp[3])) * q0.w;
        acc += __half2float(__ushort_as_half(hp[4])) * q1.x;
        acc += __half2float(__ushort_as_half(hp[5])) * q1.y;
        acc += __half2float(__ushort_as_half(hp[6])) * q1.z;
        acc += __half2float(__ushort_as_half(hp[7])) * q1.w;
    }
    for (int m = 1; m < 64; m <<= 1) acc += __shfl_xor(acc, m, 64);
    if (l == 0) out[131072 + j] = acc;
}

extern "C" void kernel_launch(void* const* d_in, const int* in_sizes, int n_in,
                              void* d_out, int out_size, void* d_ws, size_t ws_size,
                              hipStream_t stream) {
    const float* plre = (const float*)d_in[0];
    const float* plim = (const float*)d_in[1];
    const float* pldre = (const float*)d_in[2];
    const float* pldim = (const float*)d_in[3];
    const float* pvre = (const float*)d_in[4];
    const float* pvim = (const float*)d_in[5];
    const float* W2a = (const float*)d_in[6];
    const float* b2a = (const float*)d_in[7];
    const float* W2b = (const float*)d_in[8];
    const float* b2b = (const float*)d_in[9];
    const float* W1a = (const float*)d_in[10];
    const float* b1a = (const float*)d_in[11];
    const float* W1b = (const float*)d_in[12];
    const float* b1b = (const float*)d_in[13];

    char* ws = (char*)d_ws;
    float* Sa = (float*)(ws);                               // 131072 B
    unsigned short* WpF = (unsigned short*)(ws + 131072);   // 65536 B
    unsigned short* W2F = (unsigned short*)(ws + 196608);   // 32768 B
    float* Q = (float*)(ws + 229376);                       // 32768 B
    float* partial = (float*)(ws + 262144);                 // 8388608 B (32 chunks)
    unsigned short* Pws = (unsigned short*)(ws + 8650752);  // 16777216 B
    float* out = (float*)d_out;

    prep_kernel<<<256, 256, 0, stream>>>(pvre, pvim, W2a, b2a, W2b, Sa, WpF, W2F);
    mlp2_kernel<<<512, 512, 0, stream>>>(plre, plim, Sa, WpF, W2F, partial, Pws);
    dlink_norm<<<128, 512, 0, stream>>>(pvre, pvim, pldre, pldim, partial, b2b,
                                        W1a, b1a, W1b, b1b, Q, out);
    final_agg<<<256, 256, 0, stream>>>(Pws, Q, out);
}